// Round 6
// baseline (713.979 us; speedup 1.0000x reference)
//
#include <hip/hip_runtime.h>
#include <hip/hip_cooperative_groups.h>

namespace cg = cooperative_groups;

// GCN 2-layer forward for MI355X.
// out = D^-1/2 (A+I) D^-1/2 (X W) + b, twice, relu between.
// R2: CSR gather. R4: g bf16. R5: MFMA split-bf16 GEMM. R6-R8: bucketed CSR build.
// R9: XCD slicing FAILED. R10: scalar-addressed gather. R11: bf16 h2, 2-MFMA gemm2.
// R12: LDS-fused gather+gemm2 FAILED (8-node block). R13: predicated unroll-8.
// R14: dinv deferred; merged csr+gemm1 launch. R15: window-broadcast gathers ->
//      NULL (not VMEM-issue bound). R16: degree-sort -> NULL (not imbalance
//      bound). R17: gemm2 fused into gather128 epilogue (-12us).
// R18: segment phasing @ 25.6% occ -> 49us gather: latency/occupancy matters
//      below ~threshold. R19: MLP 4->8 @ full occ -> NULL => gathers are
//      LINE-SERVICE bound; all inner-loop levers (issue rate, imbalance,
//      locality, MLP) measured dead.
// R20: ONE cooperative kernel for the whole pipeline (grid=1024=4/CU,
//      grid.sync between phases). Deletes 4 launch boundaries + drain tails +
//      memset dispatch (~40us unaccounted glue). Phase bodies verbatim ->
//      bit-identical math. Fallback to classic 4-launch path if coop launch
//      is refused.

constexpr int KD = 128;      // inner dim of both GEMMs (Fin = Fh = 128)
constexpr int CHUNK = 2048;  // edges per block in scatter pass
constexpr int BCAP = 6144;   // slack capacity per bucket (mean 4096, sigma ~64)
constexpr int GRID_COOP = 1024;  // 4 blocks/CU x 256 CUs, co-resident

using short8  = __attribute__((ext_vector_type(8))) short;
using float4v = __attribute__((ext_vector_type(4))) float;
using uint4v  = __attribute__((ext_vector_type(4))) unsigned int;

// ---------------- bf16 helpers (storage = ushort, math = fp32) ----------------

__device__ __forceinline__ unsigned short f2bf(float f) {
    unsigned int u = __float_as_uint(f);
    u = (u + 0x7fffu + ((u >> 16) & 1u)) >> 16;  // round-to-nearest-even
    return (unsigned short)u;
}

__device__ __forceinline__ float2 bfpair(unsigned int u) {
    float2 f;
    f.x = __uint_as_float(u << 16);          // low short = first feature
    f.y = __uint_as_float(u & 0xffff0000u);  // high short = second feature
    return f;
}

__device__ __forceinline__ unsigned int packbf(float x, float y) {
    return (unsigned int)f2bf(x) | ((unsigned int)f2bf(y) << 16);
}

// split x = hi + lo (both bf16); subtraction is exact, |err| ~ 2^-17 |x|
__device__ __forceinline__ void bfsplit(float x, unsigned short& h, unsigned short& l) {
    h = f2bf(x);
    float fh = __uint_as_float((unsigned int)h << 16);
    l = f2bf(x - fh);
}

// ---------------------------- cooperative params -----------------------------
struct KP {
    const int* row; const int* col;
    const float* X; const float* W1; const float* b1;
    const float* W2; const float* b2;
    float* out;
    int* gcur; unsigned int* bpack; int* rowptrS; float* dinv;
    unsigned short* srow; unsigned short* g1;
    unsigned short* wth1; unsigned short* wtl1;
    unsigned short* wth2; unsigned short* wtl2;
    unsigned short* g2;
    int N, E, NBS, NB1, NBUCKET, NB2, NB3, NB4;
};

// =================== ONE cooperative kernel, 5 phases (R20) ===================
__global__ __launch_bounds__(256, 4) void gcn_fused(KP p) {
    cg::grid_group grid = cg::this_grid();

    __shared__ int s_s[256];
    __shared__ int s_lh[1024];
    __shared__ int s_lcur[1024];
    __shared__ int s_b;
    __shared__ unsigned int s_lhs[16 * 64];
    __shared__ float s_ldinv[16];

    const int t = threadIdx.x;
    const int lane = t & 63;

    // ---- phase 0: zero gcur ----
    if (blockIdx.x == 0) p.gcur[t] = 0;
    grid.sync();

    // ---- phase 1: edge scatter into slack buckets + W transpose/split ----
    for (int vb = blockIdx.x; vb < p.NB1; vb += gridDim.x) {
        if (vb >= p.NBS) {
            int id = (vb - p.NBS) * 256 + t;
            unsigned short h, l;
            if (id < 16384) {                    // W1: [128,128]
                int k = id >> 7, n = id & 127;
                bfsplit(p.W1[id], h, l);
                p.wth1[n * KD + k] = h;
                p.wtl1[n * KD + k] = l;
            } else {                             // W2: [128,64]
                int id2 = id - 16384;
                int k = id2 >> 6, n = id2 & 63;
                bfsplit(p.W2[id2], h, l);
                p.wth2[n * KD + k] = h;
                p.wtl2[n * KD + k] = l;
            }
        } else {
            int* lh = s_lh;        // [256]
            int* lbase = s_lcur;   // [256] alias
            lh[t] = 0;
            __syncthreads();
            int base = vb * CHUNK;
#pragma unroll
            for (int r = 0; r < CHUNK / 256; ++r) {
                int e = base + r * 256 + t;
                if (e < p.E) atomicAdd(&lh[p.col[e] >> 8], 1);
            }
            __syncthreads();
            int c0 = lh[t];
            lbase[t] = c0 ? (t * BCAP + atomicAdd(&p.gcur[t], c0)) : 0;
            __syncthreads();
            lh[t] = 0;  // reuse as local running offset
            __syncthreads();
#pragma unroll
            for (int r = 0; r < CHUNK / 256; ++r) {
                int e = base + r * 256 + t;
                if (e < p.E) {
                    int c = p.col[e];
                    int b = c >> 8;
                    int slot = lbase[b] + atomicAdd(&lh[b], 1);
                    p.bpack[slot] = ((unsigned int)p.row[e] << 16) | (unsigned int)c;
                }
            }
            __syncthreads();   // protect s_lh/s_lcur reuse by next vb iteration
        }
    }
    grid.sync();

    // ---- phase 2: bucketed CSR build (seg-counted) + layer-1 GEMM ----
    for (int vb = blockIdx.x; vb < p.NB2; vb += gridDim.x) {
        if (vb < p.NBUCKET) {
            int b = vb;
            int cntb = p.gcur[t];
            s_s[t] = cntb;
            __syncthreads();
            for (int off = 1; off < 256; off <<= 1) {
                int tv = (t >= off) ? s_s[t - off] : 0;
                __syncthreads();
                s_s[t] += tv;
                __syncthreads();
            }
            if (t == b) s_b = s_s[t] - cntb;  // exclusive prefix of this bucket
            if (b == 0 && t == 0) p.rowptrS[4 * p.N] = p.E;
#pragma unroll
            for (int k = 0; k < 4; ++k) s_lh[t * 4 + k] = 0;
            __syncthreads();
            int bstart = s_b;
            int nE = p.gcur[b];
            int base = b * BCAP;
            for (int i = t; i < nE; i += 256) {
                unsigned int pk = p.bpack[base + i];
                atomicAdd(&s_lh[(pk & 255) * 4 + (pk >> 30)], 1);
            }
            __syncthreads();
            int e0 = s_lh[t * 4], e1 = s_lh[t * 4 + 1];
            int e2 = s_lh[t * 4 + 2], e3 = s_lh[t * 4 + 3];
            int v = e0 + e1 + e2 + e3;
            s_s[t] = v;
            __syncthreads();
            for (int off = 1; off < 256; off <<= 1) {
                int tv = (t >= off) ? s_s[t - off] : 0;
                __syncthreads();
                s_s[t] += tv;
                __syncthreads();
            }
            int myStart = bstart + s_s[t] - v;  // exclusive
            int node = (b << 8) + t;
            if (node < p.N) {
                p.rowptrS[node * 4 + 0] = myStart;
                p.rowptrS[node * 4 + 1] = myStart + e0;
                p.rowptrS[node * 4 + 2] = myStart + e0 + e1;
                p.rowptrS[node * 4 + 3] = myStart + e0 + e1 + e2;
                p.dinv[node] = rsqrtf(1.0f + (float)v);
            }
            s_lcur[t * 4 + 0] = myStart;
            s_lcur[t * 4 + 1] = myStart + e0;
            s_lcur[t * 4 + 2] = myStart + e0 + e1;
            s_lcur[t * 4 + 3] = myStart + e0 + e1 + e2;
            __syncthreads();
            for (int i = t; i < nE; i += 256) {
                unsigned int pk = p.bpack[base + i];
                int slot = atomicAdd(&s_lcur[(pk & 255) * 4 + (pk >> 30)], 1);
                p.srow[slot] = (unsigned short)(pk >> 16);
            }
            __syncthreads();   // protect shared reuse across vb iterations
        } else {
            constexpr int FOUT = 128, NT = 8;
            int wave = t >> 6;
            int row0 = ((vb - p.NBUCKET) * 4 + wave) * 16;
            if (row0 < p.N) {
                int m = lane & 15;
                int quad = lane >> 4;

                float4v acc[NT];
#pragma unroll
                for (int ct = 0; ct < NT; ++ct) acc[ct] = (float4v){0.f, 0.f, 0.f, 0.f};

                const float* xrow = p.X + (size_t)(row0 + m) * KD + quad * 8;

#pragma unroll
                for (int ks = 0; ks < 4; ++ks) {
                    float4 xa = *(const float4*)(xrow + ks * 32);
                    float4 xb = *(const float4*)(xrow + ks * 32 + 4);
                    float xs[8] = {xa.x, xa.y, xa.z, xa.w, xb.x, xb.y, xb.z, xb.w};
                    short8 ah, al;
#pragma unroll
                    for (int j = 0; j < 8; ++j) {
                        unsigned short h, l;
                        bfsplit(xs[j], h, l);
                        ah[j] = (short)h;
                        al[j] = (short)l;
                    }
                    int koff = ks * 32 + quad * 8;
#pragma unroll
                    for (int ct = 0; ct < NT; ++ct) {
                        short8 bh = *(const short8*)(p.wth1 + (size_t)(ct * 16 + m) * KD + koff);
                        short8 bl = *(const short8*)(p.wtl1 + (size_t)(ct * 16 + m) * KD + koff);
                        acc[ct] = __builtin_amdgcn_mfma_f32_16x16x32_bf16(ah, bh, acc[ct], 0, 0, 0);
                        acc[ct] = __builtin_amdgcn_mfma_f32_16x16x32_bf16(al, bh, acc[ct], 0, 0, 0);
                        acc[ct] = __builtin_amdgcn_mfma_f32_16x16x32_bf16(ah, bl, acc[ct], 0, 0, 0);
                    }
                }

#pragma unroll
                for (int r = 0; r < 4; ++r) {
                    int row = row0 + quad * 4 + r;
#pragma unroll
                    for (int ct = 0; ct < NT; ++ct) {
                        p.g1[(size_t)row * FOUT + ct * 16 + m] = f2bf(acc[ct][r]);
                    }
                }
            }
        }
    }
    grid.sync();

    // ---- phase 3: layer-1 gather + relu + fused layer-2 GEMM ----
    for (int vb = blockIdx.x; vb < p.NB3; vb += gridDim.x) {
        int l16 = t & 15;
        int q = t >> 4;                    // block-local node 0..15
        int node = vb * 16 + q;
        bool valid = node < p.N;
        int nc = valid ? node : 0;
        int beg = p.rowptrS[nc * 4];
        int end = p.rowptrS[nc * 4 + 4];
        int deg = valid ? (end - beg) : 0;
        float dn = p.dinv[nc];
        if (l16 == 0) s_ldinv[q] = dn;

        const uint4v* Gv = (const uint4v*)(const void*)p.g1;  // row = 16 uint4

        uint4v s0 = Gv[(size_t)nc * 16 + l16];
        float ac[8];
        {
            float2 v0 = bfpair(s0[0]), v1 = bfpair(s0[1]);
            float2 v2 = bfpair(s0[2]), v3 = bfpair(s0[3]);
            ac[0] = v0.x * dn; ac[1] = v0.y * dn;
            ac[2] = v1.x * dn; ac[3] = v1.y * dn;
            ac[4] = v2.x * dn; ac[5] = v2.y * dn;
            ac[6] = v3.x * dn; ac[7] = v3.y * dn;
        }

        int dm = max(deg, __shfl_xor(deg, 16));
        dm = max(dm, __shfl_xor(dm, 32));    // wave-uniform over 4 quarters

        for (int w = 0; w < dm; w += 16) {
            int li = w + l16;
            li = (li < deg) ? li : (deg > 0 ? deg - 1 : 0);
            li += beg;
            li = (li < p.E) ? li : (p.E - 1);
            int rv = (int)p.srow[li];
            float dv = p.dinv[rv];
            int lim = dm - w;                // uniform
            for (int g = 0; g < 16 && g < lim; g += 8) {
                uint4v u[8];
                float dr[8];
#pragma unroll
                for (int j = 0; j < 8; ++j) {
                    int src = (lane & 48) | (g + j);   // own-quarter broadcast
                    int r = __shfl(rv, src);
                    dr[j] = __shfl(dv, src);
                    u[j] = Gv[(size_t)r * 16 + l16];
                }
                float sa[8] = {0.f, 0.f, 0.f, 0.f, 0.f, 0.f, 0.f, 0.f};
#pragma unroll
                for (int j = 0; j < 8; ++j) {
                    bool ok = (w + g + j) < deg;
#pragma unroll
                    for (int c = 0; c < 4; ++c) {
                        unsigned int uv = ok ? u[j][c] : 0u;
                        float2 v = bfpair(uv);
                        sa[2 * c]     = fmaf(dr[j], v.x, sa[2 * c]);
                        sa[2 * c + 1] = fmaf(dr[j], v.y, sa[2 * c + 1]);
                    }
                }
#pragma unroll
                for (int c = 0; c < 8; ++c) ac[c] += sa[c];
            }
        }

        // epilogue: h = relu(ac*dn + b1) -> bf16 pack into LDS tile
        {
            float4 bv0 = ((const float4*)p.b1)[l16 * 2];
            float4 bv1 = ((const float4*)p.b1)[l16 * 2 + 1];
            float o[8];
            o[0] = ac[0] * dn + bv0.x; o[1] = ac[1] * dn + bv0.y;
            o[2] = ac[2] * dn + bv0.z; o[3] = ac[3] * dn + bv0.w;
            o[4] = ac[4] * dn + bv1.x; o[5] = ac[5] * dn + bv1.y;
            o[6] = ac[6] * dn + bv1.z; o[7] = ac[7] * dn + bv1.w;
#pragma unroll
            for (int c = 0; c < 8; ++c) o[c] = fmaxf(o[c], 0.f);
            int lb = q * 64 + l16 * 4;
            s_lhs[lb + 0] = packbf(o[0], o[1]);
            s_lhs[lb + 1] = packbf(o[2], o[3]);
            s_lhs[lb + 2] = packbf(o[4], o[5]);
            s_lhs[lb + 3] = packbf(o[6], o[7]);
        }
        __syncthreads();

        // fused gemm2: wave ct -> 16x16 output tile (exact gemm_mfma2 sequence)
        {
            int ct = t >> 6;
            int m = lane & 15;
            int quad = lane >> 4;

            float4v acc = (float4v){0.f, 0.f, 0.f, 0.f};
#pragma unroll
            for (int ks = 0; ks < 4; ++ks) {
                short8 a = *(const short8*)&s_lhs[m * 64 + ks * 16 + quad * 4];
                int koff = ks * 32 + quad * 8;
                short8 bh = *(const short8*)(p.wth2 + (size_t)(ct * 16 + m) * KD + koff);
                short8 bl = *(const short8*)(p.wtl2 + (size_t)(ct * 16 + m) * KD + koff);
                acc = __builtin_amdgcn_mfma_f32_16x16x32_bf16(a, bh, acc, 0, 0, 0);
                acc = __builtin_amdgcn_mfma_f32_16x16x32_bf16(a, bl, acc, 0, 0, 0);
            }

#pragma unroll
            for (int r = 0; r < 4; ++r) {
                int rr = quad * 4 + r;
                int gnode = vb * 16 + rr;
                if (gnode < p.N) {
                    p.g2[(size_t)gnode * 64 + ct * 16 + m] = f2bf(acc[r] * s_ldinv[rr]);
                }
            }
        }
        __syncthreads();   // protect s_lhs/s_ldinv reuse by next vb iteration
    }
    grid.sync();

    // ---- phase 4: layer-2 gather (quarter-wave per node), fp32 nt out ----
    for (int vb = blockIdx.x; vb < p.NB4; vb += gridDim.x) {
        int tid = vb * 256 + t;
        int node = tid >> 4;
        int l16 = lane & 15;
        bool valid = node < p.N;
        int nc = valid ? node : (p.N - 1);
        int beg = p.rowptrS[nc * 4];
        int end = p.rowptrS[nc * 4 + 4];
        int deg = valid ? (end - beg) : 0;

        uint2 s0 = ((const uint2*)(const void*)p.g2)[(size_t)nc * 16 + l16];
        float2 p0 = bfpair(s0.x), p1 = bfpair(s0.y);
        float ax = p0.x, ay = p0.y, az = p1.x, aw = p1.y;

        int dm = max(deg, __shfl_xor(deg, 16));
        dm = max(dm, __shfl_xor(dm, 32));

        for (int w = 0; w < dm; w += 16) {
            int li = w + l16;
            li = (li < deg) ? li : (deg > 0 ? deg - 1 : 0);
            li += beg;
            li = (li < p.E) ? li : (p.E - 1);
            int rv = (int)p.srow[li];
            int lim = dm - w;
            for (int g = 0; g < 16 && g < lim; g += 8) {
                uint2 u[8];
#pragma unroll
                for (int j = 0; j < 8; ++j) {
                    int src = (lane & 48) | (g + j);
                    int r = __shfl(rv, src);
                    u[j] = ((const uint2*)(const void*)p.g2)[(size_t)r * 16 + l16];
                }
                float sx = 0.f, sy = 0.f, sz = 0.f, sw = 0.f;
#pragma unroll
                for (int j = 0; j < 8; ++j) {
                    bool ok = (w + g + j) < deg;
                    unsigned int ux = ok ? u[j].x : 0u;
                    unsigned int uy = ok ? u[j].y : 0u;
                    float2 v0 = bfpair(ux), v1 = bfpair(uy);
                    sx += v0.x; sy += v0.y; sz += v1.x; sw += v1.y;
                }
                ax += sx; ay += sy; az += sz; aw += sw;
            }
        }
        if (valid) {
            float s = p.dinv[nc];
            float4 bv = ((const float4*)p.b2)[l16];
            float ox = ax * s + bv.x;
            float oy = ay * s + bv.y;
            float oz = az * s + bv.z;
            float ow = aw * s + bv.w;
            float4v o = {ox, oy, oz, ow};
            __builtin_nontemporal_store(o, (float4v*)p.out + (size_t)nc * 16 + l16);
        }
    }
}

// ======================= classic fallback kernels (R19) =======================

__global__ __launch_bounds__(256) void scatter_setup(
        const int* __restrict__ row, const int* __restrict__ col,
        int* gcur, unsigned int* __restrict__ bpack, int E, int NBS,
        const float* __restrict__ W1, unsigned short* __restrict__ Wth1,
        unsigned short* __restrict__ Wtl1,
        const float* __restrict__ W2, unsigned short* __restrict__ Wth2,
        unsigned short* __restrict__ Wtl2) {
    __shared__ int lh[256];
    __shared__ int lbase[256];

    if ((int)blockIdx.x >= NBS) {
        int id = ((int)blockIdx.x - NBS) * 256 + threadIdx.x;
        unsigned short h, l;
        if (id < 16384) {
            int k = id >> 7, n = id & 127;
            bfsplit(W1[id], h, l);
            Wth1[n * KD + k] = h;
            Wtl1[n * KD + k] = l;
        } else {
            int id2 = id - 16384;
            int k = id2 >> 6, n = id2 & 63;
            bfsplit(W2[id2], h, l);
            Wth2[n * KD + k] = h;
            Wtl2[n * KD + k] = l;
        }
        return;
    }

    lh[threadIdx.x] = 0;
    __syncthreads();
    int base = (int)blockIdx.x * CHUNK;
#pragma unroll
    for (int r = 0; r < CHUNK / 256; ++r) {
        int e = base + r * 256 + threadIdx.x;
        if (e < E) atomicAdd(&lh[col[e] >> 8], 1);
    }
    __syncthreads();
    int c0 = lh[threadIdx.x];
    lbase[threadIdx.x] = c0 ? (threadIdx.x * BCAP + atomicAdd(&gcur[threadIdx.x], c0)) : 0;
    __syncthreads();
    lh[threadIdx.x] = 0;
    __syncthreads();
#pragma unroll
    for (int r = 0; r < CHUNK / 256; ++r) {
        int e = base + r * 256 + threadIdx.x;
        if (e < E) {
            int c = col[e];
            int b = c >> 8;
            int slot = lbase[b] + atomicAdd(&lh[b], 1);
            bpack[slot] = ((unsigned int)row[e] << 16) | (unsigned int)c;
        }
    }
}

__global__ __launch_bounds__(256) void csr_and_gemm1(
        const unsigned int* __restrict__ bpack, const int* __restrict__ gcur,
        int* __restrict__ rowptrS, float* __restrict__ dinv,
        unsigned short* __restrict__ srow, int N, int E, int NBUCKET,
        const float* __restrict__ X,
        const unsigned short* __restrict__ Wth,
        const unsigned short* __restrict__ Wtl,
        unsigned short* __restrict__ G) {
    __shared__ int s[256];
    __shared__ int lh[1024];
    __shared__ int lcur[1024];
    __shared__ int sh_bstart;

    if ((int)blockIdx.x < NBUCKET) {
        int b = blockIdx.x;
        int t = threadIdx.x;
        int cntb = gcur[t];
        s[t] = cntb;
        __syncthreads();
        for (int off = 1; off < 256; off <<= 1) {
            int tv = (t >= off) ? s[t - off] : 0;
            __syncthreads();
            s[t] += tv;
            __syncthreads();
        }
        if (t == b) sh_bstart = s[t] - cntb;
        if (b == 0 && t == 0) rowptrS[4 * N] = E;
#pragma unroll
        for (int k = 0; k < 4; ++k) lh[t * 4 + k] = 0;
        __syncthreads();
        int bstart = sh_bstart;
        int nE = gcur[b];
        int base = b * BCAP;
        for (int i = t; i < nE; i += 256) {
            unsigned int p = bpack[base + i];
            atomicAdd(&lh[(p & 255) * 4 + (p >> 30)], 1);
        }
        __syncthreads();
        int e0 = lh[t * 4], e1 = lh[t * 4 + 1], e2 = lh[t * 4 + 2], e3 = lh[t * 4 + 3];
        int v = e0 + e1 + e2 + e3;
        s[t] = v;
        __syncthreads();
        for (int off = 1; off < 256; off <<= 1) {
            int tv = (t >= off) ? s[t - off] : 0;
            __syncthreads();
            s[t] += tv;
            __syncthreads();
        }
        int myStart = bstart + s[t] - v;
        int node = (b << 8) + t;
        if (node < N) {
            rowptrS[node * 4 + 0] = myStart;
            rowptrS[node * 4 + 1] = myStart + e0;
            rowptrS[node * 4 + 2] = myStart + e0 + e1;
            rowptrS[node * 4 + 3] = myStart + e0 + e1 + e2;
            dinv[node] = rsqrtf(1.0f + (float)v);
        }
        lcur[t * 4 + 0] = myStart;
        lcur[t * 4 + 1] = myStart + e0;
        lcur[t * 4 + 2] = myStart + e0 + e1;
        lcur[t * 4 + 3] = myStart + e0 + e1 + e2;
        __syncthreads();
        for (int i = t; i < nE; i += 256) {
            unsigned int p = bpack[base + i];
            int slot = atomicAdd(&lcur[(p & 255) * 4 + (p >> 30)], 1);
            srow[slot] = (unsigned short)(p >> 16);
        }
    } else {
        constexpr int FOUT = 128, NT = 8;
        int wave = threadIdx.x >> 6;
        int lane = threadIdx.x & 63;
        int row0 = (((int)blockIdx.x - NBUCKET) * 4 + wave) * 16;
        if (row0 >= N) return;
        int m = lane & 15;
        int quad = lane >> 4;

        float4v acc[NT];
#pragma unroll
        for (int ct = 0; ct < NT; ++ct) acc[ct] = (float4v){0.f, 0.f, 0.f, 0.f};

        const float* xrow = X + (size_t)(row0 + m) * KD + quad * 8;

#pragma unroll
        for (int ks = 0; ks < 4; ++ks) {
            float4 xa = *(const float4*)(xrow + ks * 32);
            float4 xb = *(const float4*)(xrow + ks * 32 + 4);
            float xs[8] = {xa.x, xa.y, xa.z, xa.w, xb.x, xb.y, xb.z, xb.w};
            short8 ah, al;
#pragma unroll
            for (int j = 0; j < 8; ++j) {
                unsigned short h, l;
                bfsplit(xs[j], h, l);
                ah[j] = (short)h;
                al[j] = (short)l;
            }
            int koff = ks * 32 + quad * 8;
#pragma unroll
            for (int ct = 0; ct < NT; ++ct) {
                short8 bh = *(const short8*)(Wth + (size_t)(ct * 16 + m) * KD + koff);
                short8 bl = *(const short8*)(Wtl + (size_t)(ct * 16 + m) * KD + koff);
                acc[ct] = __builtin_amdgcn_mfma_f32_16x16x32_bf16(ah, bh, acc[ct], 0, 0, 0);
                acc[ct] = __builtin_amdgcn_mfma_f32_16x16x32_bf16(al, bh, acc[ct], 0, 0, 0);
                acc[ct] = __builtin_amdgcn_mfma_f32_16x16x32_bf16(ah, bl, acc[ct], 0, 0, 0);
            }
        }

#pragma unroll
        for (int r = 0; r < 4; ++r) {
            int row = row0 + quad * 4 + r;
#pragma unroll
            for (int ct = 0; ct < NT; ++ct) {
                G[(size_t)row * FOUT + ct * 16 + m] = f2bf(acc[ct][r]);
            }
        }
    }
}

__global__ __launch_bounds__(256) void gather128_gemm2(
        const int* __restrict__ rowptrS,
        const unsigned short* __restrict__ srow,
        const unsigned int* __restrict__ G,
        const float* __restrict__ dinv,
        const float* __restrict__ bias,
        const unsigned short* __restrict__ Wth,
        const unsigned short* __restrict__ Wtl,
        unsigned short* __restrict__ G2,
        int N, int E) {
    __shared__ unsigned int lhs[16 * 64];
    __shared__ float ldinv[16];

    int lane = threadIdx.x & 63;
    int l16 = threadIdx.x & 15;
    int q = threadIdx.x >> 4;
    int node = (int)blockIdx.x * 16 + q;
    bool valid = node < N;
    int nc = valid ? node : 0;
    int beg = rowptrS[nc * 4];
    int end = rowptrS[nc * 4 + 4];
    int deg = valid ? (end - beg) : 0;
    float dn = dinv[nc];
    if (l16 == 0) ldinv[q] = dn;

    const uint4v* Gv = (const uint4v*)G;

    uint4v s0 = Gv[(size_t)nc * 16 + l16];
    float ac[8];
    {
        float2 v0 = bfpair(s0[0]), v1 = bfpair(s0[1]);
        float2 v2 = bfpair(s0[2]), v3 = bfpair(s0[3]);
        ac[0] = v0.x * dn; ac[1] = v0.y * dn;
        ac[2] = v1.x * dn; ac[3] = v1.y * dn;
        ac[4] = v2.x * dn; ac[5] = v2.y * dn;
        ac[6] = v3.x * dn; ac[7] = v3.y * dn;
    }

    int dm = max(deg, __shfl_xor(deg, 16));
    dm = max(dm, __shfl_xor(dm, 32));

    for (int w = 0; w < dm; w += 16) {
        int li = w + l16;
        li = (li < deg) ? li : (deg > 0 ? deg - 1 : 0);
        li += beg;
        li = (li < E) ? li : (E - 1);
        int rv = (int)srow[li];
        float dv = dinv[rv];
        int lim = dm - w;
        for (int g = 0; g < 16 && g < lim; g += 8) {
            uint4v u[8];
            float dr[8];
#pragma unroll
            for (int j = 0; j < 8; ++j) {
                int src = (lane & 48) | (g + j);
                int r = __shfl(rv, src);
                dr[j] = __shfl(dv, src);
                u[j] = Gv[(size_t)r * 16 + l16];
            }
            float sa[8] = {0.f, 0.f, 0.f, 0.f, 0.f, 0.f, 0.f, 0.f};
#pragma unroll
            for (int j = 0; j < 8; ++j) {
                bool ok = (w + g + j) < deg;
#pragma unroll
                for (int c = 0; c < 4; ++c) {
                    unsigned int uv = ok ? u[j][c] : 0u;
                    float2 v = bfpair(uv);
                    sa[2 * c]     = fmaf(dr[j], v.x, sa[2 * c]);
                    sa[2 * c + 1] = fmaf(dr[j], v.y, sa[2 * c + 1]);
                }
            }
#pragma unroll
            for (int c = 0; c < 8; ++c) ac[c] += sa[c];
        }
    }

    {
        float4 bv0 = ((const float4*)bias)[l16 * 2];
        float4 bv1 = ((const float4*)bias)[l16 * 2 + 1];
        float o[8];
        o[0] = ac[0] * dn + bv0.x; o[1] = ac[1] * dn + bv0.y;
        o[2] = ac[2] * dn + bv0.z; o[3] = ac[3] * dn + bv0.w;
        o[4] = ac[4] * dn + bv1.x; o[5] = ac[5] * dn + bv1.y;
        o[6] = ac[6] * dn + bv1.z; o[7] = ac[7] * dn + bv1.w;
#pragma unroll
        for (int c = 0; c < 8; ++c) o[c] = fmaxf(o[c], 0.f);
        int lb = q * 64 + l16 * 4;
        lhs[lb + 0] = packbf(o[0], o[1]);
        lhs[lb + 1] = packbf(o[2], o[3]);
        lhs[lb + 2] = packbf(o[4], o[5]);
        lhs[lb + 3] = packbf(o[6], o[7]);
    }
    __syncthreads();

    int ct = threadIdx.x >> 6;
    int m = lane & 15;
    int quad = lane >> 4;

    float4v acc = (float4v){0.f, 0.f, 0.f, 0.f};
#pragma unroll
    for (int ks = 0; ks < 4; ++ks) {
        short8 a = *(const short8*)&lhs[m * 64 + ks * 16 + quad * 4];
        int koff = ks * 32 + quad * 8;
        short8 bh = *(const short8*)(Wth + (size_t)(ct * 16 + m) * KD + koff);
        short8 bl = *(const short8*)(Wtl + (size_t)(ct * 16 + m) * KD + koff);
        acc = __builtin_amdgcn_mfma_f32_16x16x32_bf16(a, bh, acc, 0, 0, 0);
        acc = __builtin_amdgcn_mfma_f32_16x16x32_bf16(a, bl, acc, 0, 0, 0);
    }

#pragma unroll
    for (int r = 0; r < 4; ++r) {
        int rr = quad * 4 + r;
        int gnode = (int)blockIdx.x * 16 + rr;
        if (gnode < N) {
            G2[(size_t)gnode * 64 + ct * 16 + m] = f2bf(acc[r] * ldinv[rr]);
        }
    }
}

template <bool RELU>
__global__ __launch_bounds__(256) void gather64(const int* __restrict__ rowptrS,
                                                const unsigned short* __restrict__ srow,
                                                const unsigned int* __restrict__ G,
                                                const float* __restrict__ dinv,
                                                const float* __restrict__ bias,
                                                float* __restrict__ O, int N, int E) {
    int tid = blockIdx.x * 256 + (int)threadIdx.x;
    int node = tid >> 4;
    int lane = threadIdx.x & 63;
    int l16 = lane & 15;
    bool valid = node < N;
    int nc = valid ? node : (N - 1);
    int beg = rowptrS[nc * 4];
    int end = rowptrS[nc * 4 + 4];
    int deg = valid ? (end - beg) : 0;

    uint2 s0 = ((const uint2*)G)[(size_t)nc * 16 + l16];
    float2 p0 = bfpair(s0.x), p1 = bfpair(s0.y);
    float ax = p0.x, ay = p0.y, az = p1.x, aw = p1.y;

    int dm = max(deg, __shfl_xor(deg, 16));
    dm = max(dm, __shfl_xor(dm, 32));

    for (int w = 0; w < dm; w += 16) {
        int li = w + l16;
        li = (li < deg) ? li : (deg > 0 ? deg - 1 : 0);
        li += beg;
        li = (li < E) ? li : (E - 1);
        int rv = (int)srow[li];
        int lim = dm - w;
        for (int g = 0; g < 16 && g < lim; g += 8) {
            uint2 u[8];
#pragma unroll
            for (int j = 0; j < 8; ++j) {
                int src = (lane & 48) | (g + j);
                int r = __shfl(rv, src);
                u[j] = ((const uint2*)G)[(size_t)r * 16 + l16];
            }
            float sx = 0.f, sy = 0.f, sz = 0.f, sw = 0.f;
#pragma unroll
            for (int j = 0; j < 8; ++j) {
                bool ok = (w + g + j) < deg;
                unsigned int ux = ok ? u[j].x : 0u;
                unsigned int uy = ok ? u[j].y : 0u;
                float2 v0 = bfpair(ux), v1 = bfpair(uy);
                sx += v0.x; sy += v0.y; sz += v1.x; sw += v1.y;
            }
            ax += sx; ay += sy; az += sz; aw += sw;
        }
    }
    if (!valid) return;
    float s = dinv[nc];
    float4 bv = ((const float4*)bias)[l16];
    float ox = ax * s + bv.x;
    float oy = ay * s + bv.y;
    float oz = az * s + bv.z;
    float ow = aw * s + bv.w;
    if (RELU) {
        ox = fmaxf(ox, 0.f); oy = fmaxf(oy, 0.f);
        oz = fmaxf(oz, 0.f); ow = fmaxf(ow, 0.f);
    }
    float4v o = {ox, oy, oz, ow};
    __builtin_nontemporal_store(o, (float4v*)O + (size_t)nc * 16 + l16);
}

extern "C" void kernel_launch(void* const* d_in, const int* in_sizes, int n_in,
                              void* d_out, int out_size, void* d_ws, size_t ws_size,
                              hipStream_t stream) {
    const float* x  = (const float*)d_in[0];
    const int*   ei = (const int*)d_in[1];   // int32
    const float* W1 = (const float*)d_in[2];
    const float* b1 = (const float*)d_in[3];
    const float* W2 = (const float*)d_in[4];
    const float* b2 = (const float*)d_in[5];
    float* out = (float*)d_out;

    int N = in_sizes[0] / 128;
    int E = in_sizes[1] / 2;
    const int* row = ei;       // edge_index[0]
    const int* col = ei + E;   // edge_index[1]

    // Workspace layout (all regions written before read each call)
    char* ws = (char*)d_ws;
    float* dinv    = (float*)(ws + 0x000000);            // 200 KB
    int*   rowptrS = (int*)  (ws + 0x080000);            // 800 KB + 4 (4N+1)
    int*   gcur    = (int*)  (ws + 0x150000);            // 1 KB
    unsigned short* srow = (unsigned short*)(ws + 0x160000);   // 1.6 MB
    unsigned short* g1 = (unsigned short*)(ws + 0x440000);     // 12.8 MB
    unsigned short* wth1 = (unsigned short*)(ws + 0x10C0000);  // 32 KB
    unsigned short* wtl1 = (unsigned short*)(ws + 0x10D0000);  // 32 KB
    unsigned short* wth2 = (unsigned short*)(ws + 0x10E0000);  // 16 KB
    unsigned short* wtl2 = (unsigned short*)(ws + 0x10F0000);  // 16 KB
    unsigned int* bpack = (unsigned int*)(ws + 0x1200000);     // 6.29 MB
    unsigned short* g2 = (unsigned short*)(ws + 0x2C00000);    // 6.4 MB

    int NB_BKT  = (E + CHUNK - 1) / CHUNK;   // 391
    int NBUCKET = (N + 255) / 256;           // 196
    int NB_GEMM1 = (N + 63) / 64;            // 782
    int NB_SETUP = 96;                       // 24576 transpose elems / 256
    int NB_G = (N + 15) / 16;                // 3125 (both gathers)

    KP p;
    p.row = row; p.col = col;
    p.X = x; p.W1 = W1; p.b1 = b1; p.W2 = W2; p.b2 = b2;
    p.out = out;
    p.gcur = gcur; p.bpack = bpack; p.rowptrS = rowptrS; p.dinv = dinv;
    p.srow = srow; p.g1 = g1;
    p.wth1 = wth1; p.wtl1 = wtl1; p.wth2 = wth2; p.wtl2 = wtl2;
    p.g2 = g2;
    p.N = N; p.E = E;
    p.NBS = NB_BKT; p.NB1 = NB_BKT + NB_SETUP;
    p.NBUCKET = NBUCKET; p.NB2 = NBUCKET + NB_GEMM1;
    p.NB3 = NB_G; p.NB4 = NB_G;

    void* args[] = {&p};
    hipError_t err = hipLaunchCooperativeKernel(
        (const void*)gcn_fused, dim3(GRID_COOP), dim3(256), args, 0, stream);

    if (err != hipSuccess) {
        // -------- classic 4-launch fallback (R19 path, proven) --------
        (void)hipGetLastError();
        hipMemsetAsync(gcur, 0, 256 * sizeof(int), stream);
        scatter_setup<<<NB_BKT + NB_SETUP, 256, 0, stream>>>(
            row, col, gcur, bpack, E, NB_BKT, W1, wth1, wtl1, W2, wth2, wtl2);
        csr_and_gemm1<<<NBUCKET + NB_GEMM1, 256, 0, stream>>>(
            bpack, gcur, rowptrS, dinv, srow, N, E, NBUCKET, x, wth1, wtl1, g1);
        gather128_gemm2<<<NB_G, 256, 0, stream>>>(
            rowptrS, srow, (const unsigned int*)g1, dinv, b1, wth2, wtl2, g2, N, E);
        gather64<false><<<NB_G, 256, 0, stream>>>(
            rowptrS, srow, (const unsigned int*)g2, dinv, b2, out, N, E);
    }
}

// Round 7
// 384.407 us; speedup vs baseline: 1.8574x; 1.8574x over previous
//
#include <hip/hip_runtime.h>
#include <hip/hip_cooperative_groups.h>

namespace cg = cooperative_groups;

// GCN 2-layer forward for MI355X.
// out = D^-1/2 (A+I) D^-1/2 (X W) + b, twice, relu between.
// R2: CSR gather. R4: g bf16. R5: MFMA split-bf16 GEMM. R6-R8: bucketed CSR build.
// R9: XCD slicing FAILED. R10: scalar-addressed gather. R11: bf16 h2, 2-MFMA gemm2.
// R12: LDS-fused gather+gemm2 FAILED (8-node block). R13: predicated unroll-8.
// R14: dinv deferred; merged csr+gemm1 launch. R15: window-broadcast gathers ->
//      NULL (not VMEM-issue bound). R16: degree-sort -> NULL (not imbalance
//      bound). R17: gemm2 fused into gather128 epilogue (-12us).
// R18: segment phasing @ 25.6% occ -> 49us gather (latency needs occupancy).
// R19: MLP 4->8 @ full occ -> NULL => gathers LINE-SERVICE bound.
// R20: cooperative whole-pipeline fusion -> 645us FAILED: __launch_bounds__
//      (256,4) clamped VGPR to 64 for the UNION of phases -> scratch spills
//      (WRITE_SIZE 121MB vs ~35MB true; VALU 4%, hbm 5.5% = scratch latency).
// R21: same fusion, spill fixed: launch_bounds(256) only (no min-waves),
//      phase-3 granule 8->4 (u[4]=16 VGPR, R17-validated math), grid sized by
//      hipOccupancyMaxActiveBlocksPerMultiprocessor (cached host query,
//      graph-capture safe) -> guaranteed co-residency, no trial launches.

constexpr int KD = 128;      // inner dim of both GEMMs (Fin = Fh = 128)
constexpr int CHUNK = 2048;  // edges per block in scatter pass
constexpr int BCAP = 6144;   // slack capacity per bucket (mean 4096, sigma ~64)

using short8  = __attribute__((ext_vector_type(8))) short;
using float4v = __attribute__((ext_vector_type(4))) float;
using uint4v  = __attribute__((ext_vector_type(4))) unsigned int;

// ---------------- bf16 helpers (storage = ushort, math = fp32) ----------------

__device__ __forceinline__ unsigned short f2bf(float f) {
    unsigned int u = __float_as_uint(f);
    u = (u + 0x7fffu + ((u >> 16) & 1u)) >> 16;  // round-to-nearest-even
    return (unsigned short)u;
}

__device__ __forceinline__ float2 bfpair(unsigned int u) {
    float2 f;
    f.x = __uint_as_float(u << 16);          // low short = first feature
    f.y = __uint_as_float(u & 0xffff0000u);  // high short = second feature
    return f;
}

__device__ __forceinline__ unsigned int packbf(float x, float y) {
    return (unsigned int)f2bf(x) | ((unsigned int)f2bf(y) << 16);
}

// split x = hi + lo (both bf16); subtraction is exact, |err| ~ 2^-17 |x|
__device__ __forceinline__ void bfsplit(float x, unsigned short& h, unsigned short& l) {
    h = f2bf(x);
    float fh = __uint_as_float((unsigned int)h << 16);
    l = f2bf(x - fh);
}

// ---------------------------- cooperative params -----------------------------
struct KP {
    const int* row; const int* col;
    const float* X; const float* W1; const float* b1;
    const float* W2; const float* b2;
    float* out;
    int* gcur; unsigned int* bpack; int* rowptrS; float* dinv;
    unsigned short* srow; unsigned short* g1;
    unsigned short* wth1; unsigned short* wtl1;
    unsigned short* wth2; unsigned short* wtl2;
    unsigned short* g2;
    int N, E, NBS, NB1, NBUCKET, NB2, NB3, NB4;
};

// =================== ONE cooperative kernel, 5 phases (R21) ===================
__global__ __launch_bounds__(256) void gcn_fused(KP p) {
    cg::grid_group grid = cg::this_grid();

    __shared__ int s_s[256];
    __shared__ int s_lh[1024];
    __shared__ int s_lcur[1024];
    __shared__ int s_b;
    __shared__ unsigned int s_lhs[16 * 64];
    __shared__ float s_ldinv[16];

    const int t = threadIdx.x;
    const int lane = t & 63;

    // ---- phase 0: zero gcur ----
    if (blockIdx.x == 0) p.gcur[t] = 0;
    grid.sync();

    // ---- phase 1: edge scatter into slack buckets + W transpose/split ----
    for (int vb = blockIdx.x; vb < p.NB1; vb += gridDim.x) {
        if (vb >= p.NBS) {
            int id = (vb - p.NBS) * 256 + t;
            unsigned short h, l;
            if (id < 16384) {                    // W1: [128,128]
                int k = id >> 7, n = id & 127;
                bfsplit(p.W1[id], h, l);
                p.wth1[n * KD + k] = h;
                p.wtl1[n * KD + k] = l;
            } else {                             // W2: [128,64]
                int id2 = id - 16384;
                int k = id2 >> 6, n = id2 & 63;
                bfsplit(p.W2[id2], h, l);
                p.wth2[n * KD + k] = h;
                p.wtl2[n * KD + k] = l;
            }
        } else {
            int* lh = s_lh;        // [256]
            int* lbase = s_lcur;   // [256] alias
            lh[t] = 0;
            __syncthreads();
            int base = vb * CHUNK;
#pragma unroll
            for (int r = 0; r < CHUNK / 256; ++r) {
                int e = base + r * 256 + t;
                if (e < p.E) atomicAdd(&lh[p.col[e] >> 8], 1);
            }
            __syncthreads();
            int c0 = lh[t];
            lbase[t] = c0 ? (t * BCAP + atomicAdd(&p.gcur[t], c0)) : 0;
            __syncthreads();
            lh[t] = 0;  // reuse as local running offset
            __syncthreads();
#pragma unroll
            for (int r = 0; r < CHUNK / 256; ++r) {
                int e = base + r * 256 + t;
                if (e < p.E) {
                    int c = p.col[e];
                    int b = c >> 8;
                    int slot = lbase[b] + atomicAdd(&lh[b], 1);
                    p.bpack[slot] = ((unsigned int)p.row[e] << 16) | (unsigned int)c;
                }
            }
            __syncthreads();   // protect s_lh/s_lcur reuse by next vb iteration
        }
    }
    grid.sync();

    // ---- phase 2: bucketed CSR build (seg-counted) + layer-1 GEMM ----
    for (int vb = blockIdx.x; vb < p.NB2; vb += gridDim.x) {
        if (vb < p.NBUCKET) {
            int b = vb;
            int cntb = p.gcur[t];
            s_s[t] = cntb;
            __syncthreads();
            for (int off = 1; off < 256; off <<= 1) {
                int tv = (t >= off) ? s_s[t - off] : 0;
                __syncthreads();
                s_s[t] += tv;
                __syncthreads();
            }
            if (t == b) s_b = s_s[t] - cntb;  // exclusive prefix of this bucket
            if (b == 0 && t == 0) p.rowptrS[4 * p.N] = p.E;
#pragma unroll
            for (int k = 0; k < 4; ++k) s_lh[t * 4 + k] = 0;
            __syncthreads();
            int bstart = s_b;
            int nE = p.gcur[b];
            int base = b * BCAP;
            for (int i = t; i < nE; i += 256) {
                unsigned int pk = p.bpack[base + i];
                atomicAdd(&s_lh[(pk & 255) * 4 + (pk >> 30)], 1);
            }
            __syncthreads();
            int e0 = s_lh[t * 4], e1 = s_lh[t * 4 + 1];
            int e2 = s_lh[t * 4 + 2], e3 = s_lh[t * 4 + 3];
            int v = e0 + e1 + e2 + e3;
            s_s[t] = v;
            __syncthreads();
            for (int off = 1; off < 256; off <<= 1) {
                int tv = (t >= off) ? s_s[t - off] : 0;
                __syncthreads();
                s_s[t] += tv;
                __syncthreads();
            }
            int myStart = bstart + s_s[t] - v;  // exclusive
            int node = (b << 8) + t;
            if (node < p.N) {
                p.rowptrS[node * 4 + 0] = myStart;
                p.rowptrS[node * 4 + 1] = myStart + e0;
                p.rowptrS[node * 4 + 2] = myStart + e0 + e1;
                p.rowptrS[node * 4 + 3] = myStart + e0 + e1 + e2;
                p.dinv[node] = rsqrtf(1.0f + (float)v);
            }
            s_lcur[t * 4 + 0] = myStart;
            s_lcur[t * 4 + 1] = myStart + e0;
            s_lcur[t * 4 + 2] = myStart + e0 + e1;
            s_lcur[t * 4 + 3] = myStart + e0 + e1 + e2;
            __syncthreads();
            for (int i = t; i < nE; i += 256) {
                unsigned int pk = p.bpack[base + i];
                int slot = atomicAdd(&s_lcur[(pk & 255) * 4 + (pk >> 30)], 1);
                p.srow[slot] = (unsigned short)(pk >> 16);
            }
            __syncthreads();   // protect shared reuse across vb iterations
        } else {
            constexpr int FOUT = 128, NT = 8;
            int wave = t >> 6;
            int row0 = ((vb - p.NBUCKET) * 4 + wave) * 16;
            if (row0 < p.N) {
                int m = lane & 15;
                int quad = lane >> 4;

                float4v acc[NT];
#pragma unroll
                for (int ct = 0; ct < NT; ++ct) acc[ct] = (float4v){0.f, 0.f, 0.f, 0.f};

                const float* xrow = p.X + (size_t)(row0 + m) * KD + quad * 8;

#pragma unroll
                for (int ks = 0; ks < 4; ++ks) {
                    float4 xa = *(const float4*)(xrow + ks * 32);
                    float4 xb = *(const float4*)(xrow + ks * 32 + 4);
                    float xs[8] = {xa.x, xa.y, xa.z, xa.w, xb.x, xb.y, xb.z, xb.w};
                    short8 ah, al;
#pragma unroll
                    for (int j = 0; j < 8; ++j) {
                        unsigned short h, l;
                        bfsplit(xs[j], h, l);
                        ah[j] = (short)h;
                        al[j] = (short)l;
                    }
                    int koff = ks * 32 + quad * 8;
#pragma unroll
                    for (int ct = 0; ct < NT; ++ct) {
                        short8 bh = *(const short8*)(p.wth1 + (size_t)(ct * 16 + m) * KD + koff);
                        short8 bl = *(const short8*)(p.wtl1 + (size_t)(ct * 16 + m) * KD + koff);
                        acc[ct] = __builtin_amdgcn_mfma_f32_16x16x32_bf16(ah, bh, acc[ct], 0, 0, 0);
                        acc[ct] = __builtin_amdgcn_mfma_f32_16x16x32_bf16(al, bh, acc[ct], 0, 0, 0);
                        acc[ct] = __builtin_amdgcn_mfma_f32_16x16x32_bf16(ah, bl, acc[ct], 0, 0, 0);
                    }
                }

#pragma unroll
                for (int r = 0; r < 4; ++r) {
                    int row = row0 + quad * 4 + r;
#pragma unroll
                    for (int ct = 0; ct < NT; ++ct) {
                        p.g1[(size_t)row * FOUT + ct * 16 + m] = f2bf(acc[ct][r]);
                    }
                }
            }
        }
    }
    grid.sync();

    // ---- phase 3: layer-1 gather + relu + fused layer-2 GEMM (granule 4) ----
    for (int vb = blockIdx.x; vb < p.NB3; vb += gridDim.x) {
        int l16 = t & 15;
        int q = t >> 4;                    // block-local node 0..15
        int node = vb * 16 + q;
        bool valid = node < p.N;
        int nc = valid ? node : 0;
        int beg = p.rowptrS[nc * 4];
        int end = p.rowptrS[nc * 4 + 4];
        int deg = valid ? (end - beg) : 0;
        float dn = p.dinv[nc];
        if (l16 == 0) s_ldinv[q] = dn;

        const uint4v* Gv = (const uint4v*)(const void*)p.g1;  // row = 16 uint4

        uint4v s0 = Gv[(size_t)nc * 16 + l16];
        float ac[8];
        {
            float2 v0 = bfpair(s0[0]), v1 = bfpair(s0[1]);
            float2 v2 = bfpair(s0[2]), v3 = bfpair(s0[3]);
            ac[0] = v0.x * dn; ac[1] = v0.y * dn;
            ac[2] = v1.x * dn; ac[3] = v1.y * dn;
            ac[4] = v2.x * dn; ac[5] = v2.y * dn;
            ac[6] = v3.x * dn; ac[7] = v3.y * dn;
        }

        int dm = max(deg, __shfl_xor(deg, 16));
        dm = max(dm, __shfl_xor(dm, 32));    // wave-uniform over 4 quarters

        for (int w = 0; w < dm; w += 16) {
            int li = w + l16;
            li = (li < deg) ? li : (deg > 0 ? deg - 1 : 0);
            li += beg;
            li = (li < p.E) ? li : (p.E - 1);
            int rv = (int)p.srow[li];
            float dv = p.dinv[rv];
            int lim = dm - w;                // uniform
            for (int g = 0; g < 16 && g < lim; g += 4) {
                uint4v u[4];
                float dr[4];
#pragma unroll
                for (int j = 0; j < 4; ++j) {
                    int src = (lane & 48) | (g + j);   // own-quarter broadcast
                    int r = __shfl(rv, src);
                    dr[j] = __shfl(dv, src);
                    u[j] = Gv[(size_t)r * 16 + l16];
                }
                float sa[8] = {0.f, 0.f, 0.f, 0.f, 0.f, 0.f, 0.f, 0.f};
#pragma unroll
                for (int j = 0; j < 4; ++j) {
                    bool ok = (w + g + j) < deg;
#pragma unroll
                    for (int c = 0; c < 4; ++c) {
                        unsigned int uv = ok ? u[j][c] : 0u;
                        float2 v = bfpair(uv);
                        sa[2 * c]     = fmaf(dr[j], v.x, sa[2 * c]);
                        sa[2 * c + 1] = fmaf(dr[j], v.y, sa[2 * c + 1]);
                    }
                }
#pragma unroll
                for (int c = 0; c < 8; ++c) ac[c] += sa[c];
            }
        }

        // epilogue: h = relu(ac*dn + b1) -> bf16 pack into LDS tile
        {
            float4 bv0 = ((const float4*)p.b1)[l16 * 2];
            float4 bv1 = ((const float4*)p.b1)[l16 * 2 + 1];
            float o[8];
            o[0] = ac[0] * dn + bv0.x; o[1] = ac[1] * dn + bv0.y;
            o[2] = ac[2] * dn + bv0.z; o[3] = ac[3] * dn + bv0.w;
            o[4] = ac[4] * dn + bv1.x; o[5] = ac[5] * dn + bv1.y;
            o[6] = ac[6] * dn + bv1.z; o[7] = ac[7] * dn + bv1.w;
#pragma unroll
            for (int c = 0; c < 8; ++c) o[c] = fmaxf(o[c], 0.f);
            int lb = q * 64 + l16 * 4;
            s_lhs[lb + 0] = packbf(o[0], o[1]);
            s_lhs[lb + 1] = packbf(o[2], o[3]);
            s_lhs[lb + 2] = packbf(o[4], o[5]);
            s_lhs[lb + 3] = packbf(o[6], o[7]);
        }
        __syncthreads();

        // fused gemm2: wave ct -> 16x16 output tile (exact gemm_mfma2 sequence)
        {
            int ct = t >> 6;
            int m = lane & 15;
            int quad = lane >> 4;

            float4v acc = (float4v){0.f, 0.f, 0.f, 0.f};
#pragma unroll
            for (int ks = 0; ks < 4; ++ks) {
                short8 a = *(const short8*)&s_lhs[m * 64 + ks * 16 + quad * 4];
                int koff = ks * 32 + quad * 8;
                short8 bh = *(const short8*)(p.wth2 + (size_t)(ct * 16 + m) * KD + koff);
                short8 bl = *(const short8*)(p.wtl2 + (size_t)(ct * 16 + m) * KD + koff);
                acc = __builtin_amdgcn_mfma_f32_16x16x32_bf16(a, bh, acc, 0, 0, 0);
                acc = __builtin_amdgcn_mfma_f32_16x16x32_bf16(a, bl, acc, 0, 0, 0);
            }

#pragma unroll
            for (int r = 0; r < 4; ++r) {
                int rr = quad * 4 + r;
                int gnode = vb * 16 + rr;
                if (gnode < p.N) {
                    p.g2[(size_t)gnode * 64 + ct * 16 + m] = f2bf(acc[r] * s_ldinv[rr]);
                }
            }
        }
        __syncthreads();   // protect s_lhs/s_ldinv reuse by next vb iteration
    }
    grid.sync();

    // ---- phase 4: layer-2 gather (quarter-wave per node), fp32 nt out ----
    for (int vb = blockIdx.x; vb < p.NB4; vb += gridDim.x) {
        int tid = vb * 256 + t;
        int node = tid >> 4;
        int l16 = lane & 15;
        bool valid = node < p.N;
        int nc = valid ? node : (p.N - 1);
        int beg = p.rowptrS[nc * 4];
        int end = p.rowptrS[nc * 4 + 4];
        int deg = valid ? (end - beg) : 0;

        uint2 s0 = ((const uint2*)(const void*)p.g2)[(size_t)nc * 16 + l16];
        float2 p0 = bfpair(s0.x), p1 = bfpair(s0.y);
        float ax = p0.x, ay = p0.y, az = p1.x, aw = p1.y;

        int dm = max(deg, __shfl_xor(deg, 16));
        dm = max(dm, __shfl_xor(dm, 32));

        for (int w = 0; w < dm; w += 16) {
            int li = w + l16;
            li = (li < deg) ? li : (deg > 0 ? deg - 1 : 0);
            li += beg;
            li = (li < p.E) ? li : (p.E - 1);
            int rv = (int)p.srow[li];
            int lim = dm - w;
            for (int g = 0; g < 16 && g < lim; g += 8) {
                uint2 u[8];
#pragma unroll
                for (int j = 0; j < 8; ++j) {
                    int src = (lane & 48) | (g + j);
                    int r = __shfl(rv, src);
                    u[j] = ((const uint2*)(const void*)p.g2)[(size_t)r * 16 + l16];
                }
                float sx = 0.f, sy = 0.f, sz = 0.f, sw = 0.f;
#pragma unroll
                for (int j = 0; j < 8; ++j) {
                    bool ok = (w + g + j) < deg;
                    unsigned int ux = ok ? u[j].x : 0u;
                    unsigned int uy = ok ? u[j].y : 0u;
                    float2 v0 = bfpair(ux), v1 = bfpair(uy);
                    sx += v0.x; sy += v0.y; sz += v1.x; sw += v1.y;
                }
                ax += sx; ay += sy; az += sz; aw += sw;
            }
        }
        if (valid) {
            float s = p.dinv[nc];
            float4 bv = ((const float4*)p.b2)[l16];
            float ox = ax * s + bv.x;
            float oy = ay * s + bv.y;
            float oz = az * s + bv.z;
            float ow = aw * s + bv.w;
            float4v o = {ox, oy, oz, ow};
            __builtin_nontemporal_store(o, (float4v*)p.out + (size_t)nc * 16 + l16);
        }
    }
}

// ======================= classic fallback kernels (R19) =======================

__global__ __launch_bounds__(256) void scatter_setup(
        const int* __restrict__ row, const int* __restrict__ col,
        int* gcur, unsigned int* __restrict__ bpack, int E, int NBS,
        const float* __restrict__ W1, unsigned short* __restrict__ Wth1,
        unsigned short* __restrict__ Wtl1,
        const float* __restrict__ W2, unsigned short* __restrict__ Wth2,
        unsigned short* __restrict__ Wtl2) {
    __shared__ int lh[256];
    __shared__ int lbase[256];

    if ((int)blockIdx.x >= NBS) {
        int id = ((int)blockIdx.x - NBS) * 256 + threadIdx.x;
        unsigned short h, l;
        if (id < 16384) {
            int k = id >> 7, n = id & 127;
            bfsplit(W1[id], h, l);
            Wth1[n * KD + k] = h;
            Wtl1[n * KD + k] = l;
        } else {
            int id2 = id - 16384;
            int k = id2 >> 6, n = id2 & 63;
            bfsplit(W2[id2], h, l);
            Wth2[n * KD + k] = h;
            Wtl2[n * KD + k] = l;
        }
        return;
    }

    lh[threadIdx.x] = 0;
    __syncthreads();
    int base = (int)blockIdx.x * CHUNK;
#pragma unroll
    for (int r = 0; r < CHUNK / 256; ++r) {
        int e = base + r * 256 + threadIdx.x;
        if (e < E) atomicAdd(&lh[col[e] >> 8], 1);
    }
    __syncthreads();
    int c0 = lh[threadIdx.x];
    lbase[threadIdx.x] = c0 ? (threadIdx.x * BCAP + atomicAdd(&gcur[threadIdx.x], c0)) : 0;
    __syncthreads();
    lh[threadIdx.x] = 0;
    __syncthreads();
#pragma unroll
    for (int r = 0; r < CHUNK / 256; ++r) {
        int e = base + r * 256 + threadIdx.x;
        if (e < E) {
            int c = col[e];
            int b = c >> 8;
            int slot = lbase[b] + atomicAdd(&lh[b], 1);
            bpack[slot] = ((unsigned int)row[e] << 16) | (unsigned int)c;
        }
    }
}

__global__ __launch_bounds__(256) void csr_and_gemm1(
        const unsigned int* __restrict__ bpack, const int* __restrict__ gcur,
        int* __restrict__ rowptrS, float* __restrict__ dinv,
        unsigned short* __restrict__ srow, int N, int E, int NBUCKET,
        const float* __restrict__ X,
        const unsigned short* __restrict__ Wth,
        const unsigned short* __restrict__ Wtl,
        unsigned short* __restrict__ G) {
    __shared__ int s[256];
    __shared__ int lh[1024];
    __shared__ int lcur[1024];
    __shared__ int sh_bstart;

    if ((int)blockIdx.x < NBUCKET) {
        int b = blockIdx.x;
        int t = threadIdx.x;
        int cntb = gcur[t];
        s[t] = cntb;
        __syncthreads();
        for (int off = 1; off < 256; off <<= 1) {
            int tv = (t >= off) ? s[t - off] : 0;
            __syncthreads();
            s[t] += tv;
            __syncthreads();
        }
        if (t == b) sh_bstart = s[t] - cntb;
        if (b == 0 && t == 0) rowptrS[4 * N] = E;
#pragma unroll
        for (int k = 0; k < 4; ++k) lh[t * 4 + k] = 0;
        __syncthreads();
        int bstart = sh_bstart;
        int nE = gcur[b];
        int base = b * BCAP;
        for (int i = t; i < nE; i += 256) {
            unsigned int p = bpack[base + i];
            atomicAdd(&lh[(p & 255) * 4 + (p >> 30)], 1);
        }
        __syncthreads();
        int e0 = lh[t * 4], e1 = lh[t * 4 + 1], e2 = lh[t * 4 + 2], e3 = lh[t * 4 + 3];
        int v = e0 + e1 + e2 + e3;
        s[t] = v;
        __syncthreads();
        for (int off = 1; off < 256; off <<= 1) {
            int tv = (t >= off) ? s[t - off] : 0;
            __syncthreads();
            s[t] += tv;
            __syncthreads();
        }
        int myStart = bstart + s[t] - v;
        int node = (b << 8) + t;
        if (node < N) {
            rowptrS[node * 4 + 0] = myStart;
            rowptrS[node * 4 + 1] = myStart + e0;
            rowptrS[node * 4 + 2] = myStart + e0 + e1;
            rowptrS[node * 4 + 3] = myStart + e0 + e1 + e2;
            dinv[node] = rsqrtf(1.0f + (float)v);
        }
        lcur[t * 4 + 0] = myStart;
        lcur[t * 4 + 1] = myStart + e0;
        lcur[t * 4 + 2] = myStart + e0 + e1;
        lcur[t * 4 + 3] = myStart + e0 + e1 + e2;
        __syncthreads();
        for (int i = t; i < nE; i += 256) {
            unsigned int p = bpack[base + i];
            int slot = atomicAdd(&lcur[(p & 255) * 4 + (p >> 30)], 1);
            srow[slot] = (unsigned short)(p >> 16);
        }
    } else {
        constexpr int FOUT = 128, NT = 8;
        int wave = threadIdx.x >> 6;
        int lane = threadIdx.x & 63;
        int row0 = (((int)blockIdx.x - NBUCKET) * 4 + wave) * 16;
        if (row0 >= N) return;
        int m = lane & 15;
        int quad = lane >> 4;

        float4v acc[NT];
#pragma unroll
        for (int ct = 0; ct < NT; ++ct) acc[ct] = (float4v){0.f, 0.f, 0.f, 0.f};

        const float* xrow = X + (size_t)(row0 + m) * KD + quad * 8;

#pragma unroll
        for (int ks = 0; ks < 4; ++ks) {
            float4 xa = *(const float4*)(xrow + ks * 32);
            float4 xb = *(const float4*)(xrow + ks * 32 + 4);
            float xs[8] = {xa.x, xa.y, xa.z, xa.w, xb.x, xb.y, xb.z, xb.w};
            short8 ah, al;
#pragma unroll
            for (int j = 0; j < 8; ++j) {
                unsigned short h, l;
                bfsplit(xs[j], h, l);
                ah[j] = (short)h;
                al[j] = (short)l;
            }
            int koff = ks * 32 + quad * 8;
#pragma unroll
            for (int ct = 0; ct < NT; ++ct) {
                short8 bh = *(const short8*)(Wth + (size_t)(ct * 16 + m) * KD + koff);
                short8 bl = *(const short8*)(Wtl + (size_t)(ct * 16 + m) * KD + koff);
                acc[ct] = __builtin_amdgcn_mfma_f32_16x16x32_bf16(ah, bh, acc[ct], 0, 0, 0);
                acc[ct] = __builtin_amdgcn_mfma_f32_16x16x32_bf16(al, bh, acc[ct], 0, 0, 0);
                acc[ct] = __builtin_amdgcn_mfma_f32_16x16x32_bf16(ah, bl, acc[ct], 0, 0, 0);
            }
        }

#pragma unroll
        for (int r = 0; r < 4; ++r) {
            int row = row0 + quad * 4 + r;
#pragma unroll
            for (int ct = 0; ct < NT; ++ct) {
                G[(size_t)row * FOUT + ct * 16 + m] = f2bf(acc[ct][r]);
            }
        }
    }
}

__global__ __launch_bounds__(256) void gather128_gemm2(
        const int* __restrict__ rowptrS,
        const unsigned short* __restrict__ srow,
        const unsigned int* __restrict__ G,
        const float* __restrict__ dinv,
        const float* __restrict__ bias,
        const unsigned short* __restrict__ Wth,
        const unsigned short* __restrict__ Wtl,
        unsigned short* __restrict__ G2,
        int N, int E) {
    __shared__ unsigned int lhs[16 * 64];
    __shared__ float ldinv[16];

    int lane = threadIdx.x & 63;
    int l16 = threadIdx.x & 15;
    int q = threadIdx.x >> 4;
    int node = (int)blockIdx.x * 16 + q;
    bool valid = node < N;
    int nc = valid ? node : 0;
    int beg = rowptrS[nc * 4];
    int end = rowptrS[nc * 4 + 4];
    int deg = valid ? (end - beg) : 0;
    float dn = dinv[nc];
    if (l16 == 0) ldinv[q] = dn;

    const uint4v* Gv = (const uint4v*)G;

    uint4v s0 = Gv[(size_t)nc * 16 + l16];
    float ac[8];
    {
        float2 v0 = bfpair(s0[0]), v1 = bfpair(s0[1]);
        float2 v2 = bfpair(s0[2]), v3 = bfpair(s0[3]);
        ac[0] = v0.x * dn; ac[1] = v0.y * dn;
        ac[2] = v1.x * dn; ac[3] = v1.y * dn;
        ac[4] = v2.x * dn; ac[5] = v2.y * dn;
        ac[6] = v3.x * dn; ac[7] = v3.y * dn;
    }

    int dm = max(deg, __shfl_xor(deg, 16));
    dm = max(dm, __shfl_xor(dm, 32));

    for (int w = 0; w < dm; w += 16) {
        int li = w + l16;
        li = (li < deg) ? li : (deg > 0 ? deg - 1 : 0);
        li += beg;
        li = (li < E) ? li : (E - 1);
        int rv = (int)srow[li];
        float dv = dinv[rv];
        int lim = dm - w;
        for (int g = 0; g < 16 && g < lim; g += 4) {
            uint4v u[4];
            float dr[4];
#pragma unroll
            for (int j = 0; j < 4; ++j) {
                int src = (lane & 48) | (g + j);
                int r = __shfl(rv, src);
                dr[j] = __shfl(dv, src);
                u[j] = Gv[(size_t)r * 16 + l16];
            }
            float sa[8] = {0.f, 0.f, 0.f, 0.f, 0.f, 0.f, 0.f, 0.f};
#pragma unroll
            for (int j = 0; j < 4; ++j) {
                bool ok = (w + g + j) < deg;
#pragma unroll
                for (int c = 0; c < 4; ++c) {
                    unsigned int uv = ok ? u[j][c] : 0u;
                    float2 v = bfpair(uv);
                    sa[2 * c]     = fmaf(dr[j], v.x, sa[2 * c]);
                    sa[2 * c + 1] = fmaf(dr[j], v.y, sa[2 * c + 1]);
                }
            }
#pragma unroll
            for (int c = 0; c < 8; ++c) ac[c] += sa[c];
        }
    }

    {
        float4 bv0 = ((const float4*)bias)[l16 * 2];
        float4 bv1 = ((const float4*)bias)[l16 * 2 + 1];
        float o[8];
        o[0] = ac[0] * dn + bv0.x; o[1] = ac[1] * dn + bv0.y;
        o[2] = ac[2] * dn + bv0.z; o[3] = ac[3] * dn + bv0.w;
        o[4] = ac[4] * dn + bv1.x; o[5] = ac[5] * dn + bv1.y;
        o[6] = ac[6] * dn + bv1.z; o[7] = ac[7] * dn + bv1.w;
#pragma unroll
        for (int c = 0; c < 8; ++c) o[c] = fmaxf(o[c], 0.f);
        int lb = q * 64 + l16 * 4;
        lhs[lb + 0] = packbf(o[0], o[1]);
        lhs[lb + 1] = packbf(o[2], o[3]);
        lhs[lb + 2] = packbf(o[4], o[5]);
        lhs[lb + 3] = packbf(o[6], o[7]);
    }
    __syncthreads();

    int ct = threadIdx.x >> 6;
    int m = lane & 15;
    int quad = lane >> 4;

    float4v acc = (float4v){0.f, 0.f, 0.f, 0.f};
#pragma unroll
    for (int ks = 0; ks < 4; ++ks) {
        short8 a = *(const short8*)&lhs[m * 64 + ks * 16 + quad * 4];
        int koff = ks * 32 + quad * 8;
        short8 bh = *(const short8*)(Wth + (size_t)(ct * 16 + m) * KD + koff);
        short8 bl = *(const short8*)(Wtl + (size_t)(ct * 16 + m) * KD + koff);
        acc = __builtin_amdgcn_mfma_f32_16x16x32_bf16(a, bh, acc, 0, 0, 0);
        acc = __builtin_amdgcn_mfma_f32_16x16x32_bf16(a, bl, acc, 0, 0, 0);
    }

#pragma unroll
    for (int r = 0; r < 4; ++r) {
        int rr = quad * 4 + r;
        int gnode = (int)blockIdx.x * 16 + rr;
        if (gnode < N) {
            G2[(size_t)gnode * 64 + ct * 16 + m] = f2bf(acc[r] * ldinv[rr]);
        }
    }
}

template <bool RELU>
__global__ __launch_bounds__(256) void gather64(const int* __restrict__ rowptrS,
                                                const unsigned short* __restrict__ srow,
                                                const unsigned int* __restrict__ G,
                                                const float* __restrict__ dinv,
                                                const float* __restrict__ bias,
                                                float* __restrict__ O, int N, int E) {
    int tid = blockIdx.x * 256 + (int)threadIdx.x;
    int node = tid >> 4;
    int lane = threadIdx.x & 63;
    int l16 = lane & 15;
    bool valid = node < N;
    int nc = valid ? node : (N - 1);
    int beg = rowptrS[nc * 4];
    int end = rowptrS[nc * 4 + 4];
    int deg = valid ? (end - beg) : 0;

    uint2 s0 = ((const uint2*)G)[(size_t)nc * 16 + l16];
    float2 p0 = bfpair(s0.x), p1 = bfpair(s0.y);
    float ax = p0.x, ay = p0.y, az = p1.x, aw = p1.y;

    int dm = max(deg, __shfl_xor(deg, 16));
    dm = max(dm, __shfl_xor(dm, 32));

    for (int w = 0; w < dm; w += 16) {
        int li = w + l16;
        li = (li < deg) ? li : (deg > 0 ? deg - 1 : 0);
        li += beg;
        li = (li < E) ? li : (E - 1);
        int rv = (int)srow[li];
        int lim = dm - w;
        for (int g = 0; g < 16 && g < lim; g += 8) {
            uint2 u[8];
#pragma unroll
            for (int j = 0; j < 8; ++j) {
                int src = (lane & 48) | (g + j);
                int r = __shfl(rv, src);
                u[j] = ((const uint2*)G)[(size_t)r * 16 + l16];
            }
            float sx = 0.f, sy = 0.f, sz = 0.f, sw = 0.f;
#pragma unroll
            for (int j = 0; j < 8; ++j) {
                bool ok = (w + g + j) < deg;
                unsigned int ux = ok ? u[j].x : 0u;
                unsigned int uy = ok ? u[j].y : 0u;
                float2 v0 = bfpair(ux), v1 = bfpair(uy);
                sx += v0.x; sy += v0.y; sz += v1.x; sw += v1.y;
            }
            ax += sx; ay += sy; az += sz; aw += sw;
        }
    }
    if (!valid) return;
    float s = dinv[nc];
    float4 bv = ((const float4*)bias)[l16];
    float ox = ax * s + bv.x;
    float oy = ay * s + bv.y;
    float oz = az * s + bv.z;
    float ow = aw * s + bv.w;
    if (RELU) {
        ox = fmaxf(ox, 0.f); oy = fmaxf(oy, 0.f);
        oz = fmaxf(oz, 0.f); ow = fmaxf(ow, 0.f);
    }
    float4v o = {ox, oy, oz, ow};
    __builtin_nontemporal_store(o, (float4v*)O + (size_t)nc * 16 + l16);
}

extern "C" void kernel_launch(void* const* d_in, const int* in_sizes, int n_in,
                              void* d_out, int out_size, void* d_ws, size_t ws_size,
                              hipStream_t stream) {
    const float* x  = (const float*)d_in[0];
    const int*   ei = (const int*)d_in[1];   // int32
    const float* W1 = (const float*)d_in[2];
    const float* b1 = (const float*)d_in[3];
    const float* W2 = (const float*)d_in[4];
    const float* b2 = (const float*)d_in[5];
    float* out = (float*)d_out;

    int N = in_sizes[0] / 128;
    int E = in_sizes[1] / 2;
    const int* row = ei;       // edge_index[0]
    const int* col = ei + E;   // edge_index[1]

    // Workspace layout (all regions written before read each call)
    char* ws = (char*)d_ws;
    float* dinv    = (float*)(ws + 0x000000);            // 200 KB
    int*   rowptrS = (int*)  (ws + 0x080000);            // 800 KB + 4 (4N+1)
    int*   gcur    = (int*)  (ws + 0x150000);            // 1 KB
    unsigned short* srow = (unsigned short*)(ws + 0x160000);   // 1.6 MB
    unsigned short* g1 = (unsigned short*)(ws + 0x440000);     // 12.8 MB
    unsigned short* wth1 = (unsigned short*)(ws + 0x10C0000);  // 32 KB
    unsigned short* wtl1 = (unsigned short*)(ws + 0x10D0000);  // 32 KB
    unsigned short* wth2 = (unsigned short*)(ws + 0x10E0000);  // 16 KB
    unsigned short* wtl2 = (unsigned short*)(ws + 0x10F0000);  // 16 KB
    unsigned int* bpack = (unsigned int*)(ws + 0x1200000);     // 6.29 MB
    unsigned short* g2 = (unsigned short*)(ws + 0x2C00000);    // 6.4 MB

    int NB_BKT  = (E + CHUNK - 1) / CHUNK;   // 391
    int NBUCKET = (N + 255) / 256;           // 196
    int NB_GEMM1 = (N + 63) / 64;            // 782
    int NB_SETUP = 96;                       // 24576 transpose elems / 256
    int NB_G = (N + 15) / 16;                // 3125 (both gathers)

    KP p;
    p.row = row; p.col = col;
    p.X = x; p.W1 = W1; p.b1 = b1; p.W2 = W2; p.b2 = b2;
    p.out = out;
    p.gcur = gcur; p.bpack = bpack; p.rowptrS = rowptrS; p.dinv = dinv;
    p.srow = srow; p.g1 = g1;
    p.wth1 = wth1; p.wtl1 = wtl1; p.wth2 = wth2; p.wtl2 = wtl2;
    p.g2 = g2;
    p.N = N; p.E = E;
    p.NBS = NB_BKT; p.NB1 = NB_BKT + NB_SETUP;
    p.NBUCKET = NBUCKET; p.NB2 = NBUCKET + NB_GEMM1;
    p.NB3 = NB_G; p.NB4 = NB_G;

    // ---- validated cooperative grid size (cached host queries, capture-safe) ----
    static int coop_grid = -2;   // -2 = not yet probed
    if (coop_grid == -2) {
        int blocksPerCU = 0;
        hipError_t e1 = hipOccupancyMaxActiveBlocksPerMultiprocessor(
            &blocksPerCU, gcn_fused, 256, 0);
        hipDeviceProp_t prop;
        hipError_t e2 = hipGetDeviceProperties(&prop, 0);
        if (e1 == hipSuccess && e2 == hipSuccess && blocksPerCU >= 1) {
            int bpc = blocksPerCU < 8 ? blocksPerCU : 8;
            coop_grid = bpc * prop.multiProcessorCount;
        } else {
            coop_grid = -1;      // cooperative path unavailable
        }
        (void)hipGetLastError();
    }

    bool done = false;
    if (coop_grid > 0) {
        void* args[] = {&p};
        hipError_t err = hipLaunchCooperativeKernel(
            (const void*)gcn_fused, dim3(coop_grid), dim3(256), args, 0, stream);
        if (err == hipSuccess) {
            done = true;
        } else {
            (void)hipGetLastError();
            coop_grid = -1;      // never retry cooperative on this device
        }
    }

    if (!done) {
        // -------- classic 4-launch fallback (R19 path, proven) --------
        hipMemsetAsync(gcur, 0, 256 * sizeof(int), stream);
        scatter_setup<<<NB_BKT + NB_SETUP, 256, 0, stream>>>(
            row, col, gcur, bpack, E, NB_BKT, W1, wth1, wtl1, W2, wth2, wtl2);
        csr_and_gemm1<<<NBUCKET + NB_GEMM1, 256, 0, stream>>>(
            bpack, gcur, rowptrS, dinv, srow, N, E, NBUCKET, x, wth1, wtl1, g1);
        gather128_gemm2<<<NB_G, 256, 0, stream>>>(
            rowptrS, srow, (const unsigned int*)g1, dinv, b1, wth2, wtl2, g2, N, E);
        gather64<false><<<NB_G, 256, 0, stream>>>(
            rowptrS, srow, (const unsigned int*)g2, dinv, b2, out, N, E);
    }
}

// Round 8
// 215.149 us; speedup vs baseline: 3.3185x; 1.7867x over previous
//
#include <hip/hip_runtime.h>

// GCN 2-layer forward for MI355X.
// out = D^-1/2 (A+I) D^-1/2 (X W) + b, twice, relu between.
// R2: CSR gather. R4: g bf16. R5: MFMA split-bf16 GEMM. R6-R8: bucketed CSR build.
// R9: XCD slicing FAILED. R10: scalar-addressed gather. R11: bf16 h2, 2-MFMA gemm2.
// R12: LDS-fused gather+gemm2 FAILED. R13: predicated unroll-8.
// R14: dinv deferred; merged csr+gemm1 launch. R15: window-broadcast gathers ->
//      NULL (not VMEM-issue bound). R16: degree-sort -> NULL (not imbalance).
// R17: gemm2 fused into gather128 epilogue (-12us, 182.6us best).
// R18: source-segmentation @ 782 blocks -> occupancy loss, +8.5us.
// R19: MLP x2 @ full occ -> NULL => gathers are random-LINE-THROUGHPUT bound
//      (~64 G-lines/s = L3 service rate; g1 fits L3 but NOT 4MB/XCD L2).
// R20/R21: cooperative whole-pipeline fusion FAILED twice (spills; then
//      residency-capped grid -> 24% occupancy). Abandoned.
// R22: FEATURE-chunked gathers. h[n][f] is independent per f -> slice columns:
//      gather128 = 4 chunks x 32 feats (3.2MB slice, fits per-XCD L2);
//      gather64 = 2 chunks x 32 feats. grid = chunk*NTILE+tile: dispatch order
//      keeps resident blocks within one chunk -> device-wide slice locality at
//      FULL occupancy, no sync (perf-only). gemm2 unfused back to R11 kernel
//      (h2 overlaps dead bpack). Per-feature sum order identical -> same absmax.

constexpr int KD = 128;      // inner dim of both GEMMs (Fin = Fh = 128)
constexpr int CHUNK = 2048;  // edges per block in scatter pass
constexpr int BCAP = 6144;   // slack capacity per bucket (mean 4096, sigma ~64)

using short8  = __attribute__((ext_vector_type(8))) short;
using float4v = __attribute__((ext_vector_type(4))) float;

// ---------------- bf16 helpers (storage = ushort, math = fp32) ----------------

__device__ __forceinline__ unsigned short f2bf(float f) {
    unsigned int u = __float_as_uint(f);
    u = (u + 0x7fffu + ((u >> 16) & 1u)) >> 16;  // round-to-nearest-even
    return (unsigned short)u;
}

__device__ __forceinline__ float2 bfpair(unsigned int u) {
    float2 f;
    f.x = __uint_as_float(u << 16);          // low short = first feature
    f.y = __uint_as_float(u & 0xffff0000u);  // high short = second feature
    return f;
}

__device__ __forceinline__ unsigned int packbf(float x, float y) {
    return (unsigned int)f2bf(x) | ((unsigned int)f2bf(y) << 16);
}

// split x = hi + lo (both bf16); subtraction is exact, |err| ~ 2^-17 |x|
__device__ __forceinline__ void bfsplit(float x, unsigned short& h, unsigned short& l) {
    h = f2bf(x);
    float fh = __uint_as_float((unsigned int)h << 16);
    l = f2bf(x - fh);
}

// ------- MERGED: bucket_scatter (blocks [0,NBS)) + W transpose (rest) -------
// gcur must be zeroed (hipMemsetAsync) before this launch; counts zero-based.
__global__ __launch_bounds__(256) void scatter_setup(
        const int* __restrict__ row, const int* __restrict__ col,
        int* gcur, unsigned int* __restrict__ bpack, int E, int NBS,
        const float* __restrict__ W1, unsigned short* __restrict__ Wth1,
        unsigned short* __restrict__ Wtl1,
        const float* __restrict__ W2, unsigned short* __restrict__ Wth2,
        unsigned short* __restrict__ Wtl2) {
    __shared__ int lh[256];
    __shared__ int lbase[256];

    if ((int)blockIdx.x >= NBS) {
        // -------- weight transpose + split (96 blocks x 256 = 24576 elems) ----
        int id = ((int)blockIdx.x - NBS) * 256 + threadIdx.x;
        unsigned short h, l;
        if (id < 16384) {                    // W1: [128,128]
            int k = id >> 7, n = id & 127;
            bfsplit(W1[id], h, l);
            Wth1[n * KD + k] = h;
            Wtl1[n * KD + k] = l;
        } else {                             // W2: [128,64]
            int id2 = id - 16384;
            int k = id2 >> 6, n = id2 & 63;
            bfsplit(W2[id2], h, l);
            Wth2[n * KD + k] = h;
            Wtl2[n * KD + k] = l;
        }
        return;
    }

    // -------- edge scatter into slack buckets; record = (row<<16)|col --------
    lh[threadIdx.x] = 0;
    __syncthreads();
    int base = (int)blockIdx.x * CHUNK;
#pragma unroll
    for (int r = 0; r < CHUNK / 256; ++r) {
        int e = base + r * 256 + threadIdx.x;
        if (e < E) atomicAdd(&lh[col[e] >> 8], 1);
    }
    __syncthreads();
    int c0 = lh[threadIdx.x];
    lbase[threadIdx.x] = c0 ? (threadIdx.x * BCAP + atomicAdd(&gcur[threadIdx.x], c0)) : 0;
    __syncthreads();
    lh[threadIdx.x] = 0;  // reuse as local running offset
    __syncthreads();
#pragma unroll
    for (int r = 0; r < CHUNK / 256; ++r) {
        int e = base + r * 256 + threadIdx.x;
        if (e < E) {
            int c = col[e];
            int b = c >> 8;
            int slot = lbase[b] + atomicAdd(&lh[b], 1);
            bpack[slot] = ((unsigned int)row[e] << 16) | (unsigned int)c;
        }
    }
}

// ------- MERGED: bucket_csr (blocks [0,NBUCKET)) + layer-1 GEMM (rest) -------
__global__ __launch_bounds__(256) void csr_and_gemm1(
        const unsigned int* __restrict__ bpack, const int* __restrict__ gcur,
        int* __restrict__ rowptrS, float* __restrict__ dinv,
        unsigned short* __restrict__ srow, int N, int E, int NBUCKET,
        const float* __restrict__ X,
        const unsigned short* __restrict__ Wth,
        const unsigned short* __restrict__ Wtl,
        unsigned short* __restrict__ G) {
    __shared__ int s[256];
    __shared__ int lh[1024];
    __shared__ int lcur[1024];
    __shared__ int sh_bstart;

    if ((int)blockIdx.x < NBUCKET) {
        // ---------------- CSR build (seg-counted, R18 layout) ----------------
        int b = blockIdx.x;
        int t = threadIdx.x;
        int cntb = gcur[t];
        s[t] = cntb;
        __syncthreads();
        for (int off = 1; off < 256; off <<= 1) {
            int tv = (t >= off) ? s[t - off] : 0;
            __syncthreads();
            s[t] += tv;
            __syncthreads();
        }
        if (t == b) sh_bstart = s[t] - cntb;
        if (b == 0 && t == 0) rowptrS[4 * N] = E;
#pragma unroll
        for (int k = 0; k < 4; ++k) lh[t * 4 + k] = 0;
        __syncthreads();
        int bstart = sh_bstart;
        int nE = gcur[b];
        int base = b * BCAP;
        for (int i = t; i < nE; i += 256) {
            unsigned int p = bpack[base + i];
            atomicAdd(&lh[(p & 255) * 4 + (p >> 30)], 1);
        }
        __syncthreads();
        int e0 = lh[t * 4], e1 = lh[t * 4 + 1], e2 = lh[t * 4 + 2], e3 = lh[t * 4 + 3];
        int v = e0 + e1 + e2 + e3;
        s[t] = v;
        __syncthreads();
        for (int off = 1; off < 256; off <<= 1) {
            int tv = (t >= off) ? s[t - off] : 0;
            __syncthreads();
            s[t] += tv;
            __syncthreads();
        }
        int myStart = bstart + s[t] - v;
        int node = (b << 8) + t;
        if (node < N) {
            rowptrS[node * 4 + 0] = myStart;
            rowptrS[node * 4 + 1] = myStart + e0;
            rowptrS[node * 4 + 2] = myStart + e0 + e1;
            rowptrS[node * 4 + 3] = myStart + e0 + e1 + e2;
            dinv[node] = rsqrtf(1.0f + (float)v);
        }
        lcur[t * 4 + 0] = myStart;
        lcur[t * 4 + 1] = myStart + e0;
        lcur[t * 4 + 2] = myStart + e0 + e1;
        lcur[t * 4 + 3] = myStart + e0 + e1 + e2;
        __syncthreads();
        for (int i = t; i < nE; i += 256) {
            unsigned int p = bpack[base + i];
            int slot = atomicAdd(&lcur[(p & 255) * 4 + (p >> 30)], 1);
            srow[slot] = (unsigned short)(p >> 16);
        }
    } else {
        // ---------------- layer-1 GEMM (split-A, 3 MFMAs, no dinv) ----------
        constexpr int FOUT = 128, NT = 8;
        int wave = threadIdx.x >> 6;
        int lane = threadIdx.x & 63;
        int row0 = (((int)blockIdx.x - NBUCKET) * 4 + wave) * 16;
        if (row0 >= N) return;
        int m = lane & 15;
        int quad = lane >> 4;

        float4v acc[NT];
#pragma unroll
        for (int ct = 0; ct < NT; ++ct) acc[ct] = (float4v){0.f, 0.f, 0.f, 0.f};

        const float* xrow = X + (size_t)(row0 + m) * KD + quad * 8;

#pragma unroll
        for (int ks = 0; ks < 4; ++ks) {
            float4 xa = *(const float4*)(xrow + ks * 32);
            float4 xb = *(const float4*)(xrow + ks * 32 + 4);
            float xs[8] = {xa.x, xa.y, xa.z, xa.w, xb.x, xb.y, xb.z, xb.w};
            short8 ah, al;
#pragma unroll
            for (int j = 0; j < 8; ++j) {
                unsigned short h, l;
                bfsplit(xs[j], h, l);
                ah[j] = (short)h;
                al[j] = (short)l;
            }
            int koff = ks * 32 + quad * 8;
#pragma unroll
            for (int ct = 0; ct < NT; ++ct) {
                short8 bh = *(const short8*)(Wth + (size_t)(ct * 16 + m) * KD + koff);
                short8 bl = *(const short8*)(Wtl + (size_t)(ct * 16 + m) * KD + koff);
                acc[ct] = __builtin_amdgcn_mfma_f32_16x16x32_bf16(ah, bh, acc[ct], 0, 0, 0);
                acc[ct] = __builtin_amdgcn_mfma_f32_16x16x32_bf16(al, bh, acc[ct], 0, 0, 0);
                acc[ct] = __builtin_amdgcn_mfma_f32_16x16x32_bf16(ah, bl, acc[ct], 0, 0, 0);
            }
        }

#pragma unroll
        for (int r = 0; r < 4; ++r) {
            int row = row0 + quad * 4 + r;
#pragma unroll
            for (int ct = 0; ct < NT; ++ct) {
                G[(size_t)row * FOUT + ct * 16 + m] = f2bf(acc[ct][r]);
            }
        }
    }
}

// ---------- R22: layer-1 gather, FEATURE-CHUNKED (4 x 32 features) ----------
// grid = 4*NTILE; tile = bid % NTILE, chunk = bid / NTILE -> dispatch order
// keeps all resident blocks in one chunk => working set 3.2MB (per-XCD L2).
// Quarter-wave per node; lane owns 2 features (1 uint) of the chunk.
// Per-feature edge-summation tree identical to R17 (granule 4).
__global__ __launch_bounds__(256) void gather128_chunk(
        const int* __restrict__ rowptrS,
        const unsigned short* __restrict__ srow,
        const unsigned int* __restrict__ G,      // g1 bf16x2 [N][64]
        const float* __restrict__ dinv,
        const float* __restrict__ bias,          // b1
        unsigned int* __restrict__ H2,           // h bf16x2 [N][64] out
        int N, int E, int NTILE) {
    int tile = (int)blockIdx.x % NTILE;
    int c    = (int)blockIdx.x / NTILE;          // feature chunk 0..3
    int lane = threadIdx.x & 63;
    int l16  = threadIdx.x & 15;
    int q    = threadIdx.x >> 4;                 // node in tile
    int node = tile * 16 + q;
    bool valid = node < N;
    int nc = valid ? node : 0;
    int beg = rowptrS[nc * 4];
    int end = rowptrS[nc * 4 + 4];
    int deg = valid ? (end - beg) : 0;
    float dn = dinv[nc];

    // self-loop (x dinv[n]); this lane's uint = features [c*32+l16*2, +2)
    unsigned int su = G[(size_t)nc * 64 + c * 16 + l16];
    float2 sv = bfpair(su);
    float a0 = sv.x * dn, a1 = sv.y * dn;

    int dm = max(deg, __shfl_xor(deg, 16));
    dm = max(dm, __shfl_xor(dm, 32));            // wave-uniform over 4 quarters

    for (int w = 0; w < dm; w += 16) {
        int li = w + l16;
        li = (li < deg) ? li : (deg > 0 ? deg - 1 : 0);
        li += beg;
        li = (li < E) ? li : (E - 1);
        int rv = (int)srow[li];
        float dv = dinv[rv];
        int lim = dm - w;                        // uniform
        for (int g = 0; g < 16 && g < lim; g += 4) {
            unsigned int u[4];
            float dr[4];
#pragma unroll
            for (int j = 0; j < 4; ++j) {
                int src = (lane & 48) | (g + j); // broadcast within own quarter
                int r = __shfl(rv, src);
                dr[j] = __shfl(dv, src);
                u[j] = G[(size_t)r * 64 + c * 16 + l16];
            }
            float s0 = 0.f, s1 = 0.f;
#pragma unroll
            for (int j = 0; j < 4; ++j) {
                bool ok = (w + g + j) < deg;
                unsigned int uv = ok ? u[j] : 0u;
                float2 v = bfpair(uv);
                s0 = fmaf(dr[j], v.x, s0);
                s1 = fmaf(dr[j], v.y, s1);
            }
            a0 += s0; a1 += s1;
        }
    }
    if (!valid) return;
    float2 bv = ((const float2*)bias)[c * 16 + l16];
    float o0 = fmaxf(a0 * dn + bv.x, 0.f);
    float o1 = fmaxf(a1 * dn + bv.y, 0.f);
    H2[(size_t)nc * 64 + c * 16 + l16] = packbf(o0, o1);
}

// -------- layer-2 GEMM (bf16 in): G2 = bf16(dinv*(H@W2)) -- R11 kernel --------
__global__ __launch_bounds__(256) void gemm_mfma2(const unsigned short* __restrict__ H,
                                                  const unsigned short* __restrict__ Wth,
                                                  const unsigned short* __restrict__ Wtl,
                                                  const float* __restrict__ dinv,
                                                  unsigned short* __restrict__ G, int N) {
    constexpr int FOUT = 64, NT = 4;
    int wave = threadIdx.x >> 6;
    int lane = threadIdx.x & 63;
    int row0 = (blockIdx.x * 4 + wave) * 16;
    if (row0 >= N) return;
    int m = lane & 15;
    int quad = lane >> 4;

    float4v acc[NT];
#pragma unroll
    for (int ct = 0; ct < NT; ++ct) acc[ct] = (float4v){0.f, 0.f, 0.f, 0.f};

    const unsigned short* hrow = H + (size_t)(row0 + m) * KD + quad * 8;

#pragma unroll
    for (int ks = 0; ks < 4; ++ks) {
        short8 a = *(const short8*)(hrow + ks * 32);
        int koff = ks * 32 + quad * 8;
#pragma unroll
        for (int ct = 0; ct < NT; ++ct) {
            short8 bh = *(const short8*)(Wth + (size_t)(ct * 16 + m) * KD + koff);
            short8 bl = *(const short8*)(Wtl + (size_t)(ct * 16 + m) * KD + koff);
            acc[ct] = __builtin_amdgcn_mfma_f32_16x16x32_bf16(a, bh, acc[ct], 0, 0, 0);
            acc[ct] = __builtin_amdgcn_mfma_f32_16x16x32_bf16(a, bl, acc[ct], 0, 0, 0);
        }
    }

#pragma unroll
    for (int r = 0; r < 4; ++r) {
        int row = row0 + quad * 4 + r;
        float s = dinv[row];
#pragma unroll
        for (int ct = 0; ct < 4; ++ct) {
            G[(size_t)row * FOUT + ct * 16 + m] = f2bf(acc[ct][r] * s);
        }
    }
}

// ---------- R22: layer-2 gather, FEATURE-CHUNKED (2 x 32 features) ----------
// grid = 2*NTILE; same dispatch-order slicing (3.2MB per chunk). Quarter-wave
// per node; lane owns 2 features. Granule 8 (matches prior gather64 tree).
__global__ __launch_bounds__(256) void gather64_chunk(
        const int* __restrict__ rowptrS,
        const unsigned short* __restrict__ srow,
        const unsigned int* __restrict__ G,      // g2 bf16x2 [N][32]
        const float* __restrict__ dinv,
        const float* __restrict__ bias,          // b2
        float* __restrict__ O, int N, int E, int NTILE) {
    int tile = (int)blockIdx.x % NTILE;
    int c    = (int)blockIdx.x / NTILE;          // feature chunk 0..1
    int lane = threadIdx.x & 63;
    int l16  = threadIdx.x & 15;
    int q    = threadIdx.x >> 4;
    int node = tile * 16 + q;
    bool valid = node < N;
    int nc = valid ? node : (N - 1);
    int beg = rowptrS[nc * 4];
    int end = rowptrS[nc * 4 + 4];
    int deg = valid ? (end - beg) : 0;

    unsigned int su = G[(size_t)nc * 32 + c * 16 + l16];   // self-loop
    float2 sv = bfpair(su);
    float a0 = sv.x, a1 = sv.y;

    int dm = max(deg, __shfl_xor(deg, 16));
    dm = max(dm, __shfl_xor(dm, 32));

    for (int w = 0; w < dm; w += 16) {
        int li = w + l16;
        li = (li < deg) ? li : (deg > 0 ? deg - 1 : 0);
        li += beg;
        li = (li < E) ? li : (E - 1);
        int rv = (int)srow[li];
        int lim = dm - w;
        for (int g = 0; g < 16 && g < lim; g += 8) {
            unsigned int u[8];
#pragma unroll
            for (int j = 0; j < 8; ++j) {
                int src = (lane & 48) | (g + j);
                int r = __shfl(rv, src);
                u[j] = G[(size_t)r * 32 + c * 16 + l16];
            }
            float s0 = 0.f, s1 = 0.f;
#pragma unroll
            for (int j = 0; j < 8; ++j) {
                bool ok = (w + g + j) < deg;
                unsigned int uv = ok ? u[j] : 0u;
                float2 v = bfpair(uv);
                s0 += v.x; s1 += v.y;
            }
            a0 += s0; a1 += s1;
        }
    }
    if (!valid) return;
    float s = dinv[nc];
    float2 bv = ((const float2*)bias)[c * 16 + l16];
    float2 o = make_float2(a0 * s + bv.x, a1 * s + bv.y);
    unsigned long long pv;
    __builtin_memcpy(&pv, &o, 8);
    __builtin_nontemporal_store(pv,
        (unsigned long long*)&((float2*)O)[(size_t)nc * 32 + c * 16 + l16]);
}

extern "C" void kernel_launch(void* const* d_in, const int* in_sizes, int n_in,
                              void* d_out, int out_size, void* d_ws, size_t ws_size,
                              hipStream_t stream) {
    const float* x  = (const float*)d_in[0];
    const int*   ei = (const int*)d_in[1];   // int32
    const float* W1 = (const float*)d_in[2];
    const float* b1 = (const float*)d_in[3];
    const float* W2 = (const float*)d_in[4];
    const float* b2 = (const float*)d_in[5];
    float* out = (float*)d_out;

    int N = in_sizes[0] / 128;
    int E = in_sizes[1] / 2;
    const int* row = ei;       // edge_index[0]
    const int* col = ei + E;   // edge_index[1]

    // Workspace layout (all regions written before read each call)
    char* ws = (char*)d_ws;
    float* dinv    = (float*)(ws + 0x000000);            // 200 KB
    int*   rowptrS = (int*)  (ws + 0x080000);            // 800 KB + 4 (4N+1)
    int*   gcur    = (int*)  (ws + 0x150000);            // 1 KB
    unsigned short* srow = (unsigned short*)(ws + 0x160000);   // 1.6 MB
    unsigned short* g1 = (unsigned short*)(ws + 0x440000);     // 12.8 MB
    unsigned short* wth1 = (unsigned short*)(ws + 0x10C0000);  // 32 KB
    unsigned short* wtl1 = (unsigned short*)(ws + 0x10D0000);  // 32 KB
    unsigned short* wth2 = (unsigned short*)(ws + 0x10E0000);  // 16 KB
    unsigned short* wtl2 = (unsigned short*)(ws + 0x10F0000);  // 16 KB
    // bpack (6.29 MB) overlaps h2: consumed by csr_and_gemm1 before
    // gather128_chunk first writes h2 (R14 trick).
    unsigned int* bpack = (unsigned int*)(ws + 0x1200000);     // 6.29 MB
    unsigned short* h2 = (unsigned short*)(ws + 0x1200000);    // 12.8 MB (bf16)
    unsigned short* g2 = (unsigned short*)(ws + 0x2C00000);    // 6.4 MB

    int NB_BKT  = (E + CHUNK - 1) / CHUNK;   // 391
    int NBUCKET = (N + 255) / 256;           // 196
    int NB_GEMM1 = (N + 63) / 64;            // 782
    int NB_SETUP = 96;                       // 24576 transpose elems / 256
    int NTILE = (N + 15) / 16;               // 3125

    // ---- gcur zero + merged scatter/setup + merged CSR/GEMM1 ----
    hipMemsetAsync(gcur, 0, 256 * sizeof(int), stream);
    scatter_setup<<<NB_BKT + NB_SETUP, 256, 0, stream>>>(
        row, col, gcur, bpack, E, NB_BKT, W1, wth1, wtl1, W2, wth2, wtl2);
    csr_and_gemm1<<<NBUCKET + NB_GEMM1, 256, 0, stream>>>(
        bpack, gcur, rowptrS, dinv, srow, N, E, NBUCKET, x, wth1, wtl1, g1);

    // ---- layer-1 gather, feature-chunked (4 chunks x 3.2MB slice) ----
    gather128_chunk<<<4 * NTILE, 256, 0, stream>>>(
        rowptrS, srow, (const unsigned int*)g1, dinv, b1,
        (unsigned int*)h2, N, E, NTILE);

    // ---- layer-2 GEMM (separate launch; exact R11 kernel) ----
    gemm_mfma2<<<NB_GEMM1, 256, 0, stream>>>(h2, wth2, wtl2, dinv, g2, N);

    // ---- layer-2 gather, feature-chunked (2 chunks x 3.2MB slice) ----
    gather64_chunk<<<2 * NTILE, 256, 0, stream>>>(
        rowptrS, srow, (const unsigned int*)g2, dinv, b2, out, N, E, NTILE);
}

// Round 9
// 181.721 us; speedup vs baseline: 3.9290x; 1.1840x over previous
//
#include <hip/hip_runtime.h>

// GCN 2-layer forward for MI355X.
// out = D^-1/2 (A+I) D^-1/2 (X W) + b, twice, relu between.
// R2: CSR gather. R4: g bf16. R5: MFMA split-bf16 GEMM. R6-R8: bucketed CSR build.
// R9: XCD slicing FAILED. R10: scalar-addressed gather. R11: bf16 h2, 2-MFMA gemm2.
// R12: LDS-fused gather+gemm2 FAILED (8-node block). R13: predicated unroll-8.
// R14: dinv deferred; merged csr+gemm1 launch. R15: window-broadcast gathers ->
//      NULL (not VMEM-issue bound). R16: degree-sort -> NULL (not imbalance).
// R17: gemm2 fused into gather128 epilogue (BEST: 182.6us).
// R18: source segments -> occupancy loss. R19: MLP x2 -> NULL (line-service
//      bound). R20/R21: cooperative fusion FAILED (spill; residency cap).
// R22: feature-chunked gathers -> 215us. FETCH 114.7MB = 8-XCD slice broadcast
//      confirmed: random connectivity makes aggregate L3->L2 traffic ~8x matrix
//      size REGARDLESS of partitioning. Locality family closed (R9/R18/R22).
// R23: revert to R17 verbatim + predication moved to the MULTIPLIER:
//      gather128 zeroes dr[j] (1 cndmask/edge) instead of 4 uint masks
//      (fmaf(0,v,s)==s, v always finite); gather64 uses fmaf(m,v,s) with
//      m in {0,1} (fmaf(1,v,s) rounds == s+v). Bit-identical, ~14% fewer
//      gather-loop VALU ops (VALUBusy was 42% co-limit in R22 counters).

constexpr int KD = 128;      // inner dim of both GEMMs (Fin = Fh = 128)
constexpr int CHUNK = 2048;  // edges per block in scatter pass
constexpr int BCAP = 6144;   // slack capacity per bucket (mean 4096, sigma ~64)

using short8  = __attribute__((ext_vector_type(8))) short;
using float4v = __attribute__((ext_vector_type(4))) float;
using uint4v  = __attribute__((ext_vector_type(4))) unsigned int;

// ---------------- bf16 helpers (storage = ushort, math = fp32) ----------------

__device__ __forceinline__ unsigned short f2bf(float f) {
    unsigned int u = __float_as_uint(f);
    u = (u + 0x7fffu + ((u >> 16) & 1u)) >> 16;  // round-to-nearest-even
    return (unsigned short)u;
}

__device__ __forceinline__ float2 bfpair(unsigned int u) {
    float2 f;
    f.x = __uint_as_float(u << 16);          // low short = first feature
    f.y = __uint_as_float(u & 0xffff0000u);  // high short = second feature
    return f;
}

__device__ __forceinline__ unsigned int packbf(float x, float y) {
    return (unsigned int)f2bf(x) | ((unsigned int)f2bf(y) << 16);
}

// split x = hi + lo (both bf16); subtraction is exact, |err| ~ 2^-17 |x|
__device__ __forceinline__ void bfsplit(float x, unsigned short& h, unsigned short& l) {
    h = f2bf(x);
    float fh = __uint_as_float((unsigned int)h << 16);
    l = f2bf(x - fh);
}

// ------- MERGED: bucket_scatter (blocks [0,NBS)) + W transpose (rest) -------
// gcur must be zeroed (hipMemsetAsync) before this launch; counts zero-based.
__global__ __launch_bounds__(256) void scatter_setup(
        const int* __restrict__ row, const int* __restrict__ col,
        int* gcur, unsigned int* __restrict__ bpack, int E, int NBS,
        const float* __restrict__ W1, unsigned short* __restrict__ Wth1,
        unsigned short* __restrict__ Wtl1,
        const float* __restrict__ W2, unsigned short* __restrict__ Wth2,
        unsigned short* __restrict__ Wtl2) {
    __shared__ int lh[256];
    __shared__ int lbase[256];

    if ((int)blockIdx.x >= NBS) {
        // -------- weight transpose + split (96 blocks x 256 = 24576 elems) ----
        int id = ((int)blockIdx.x - NBS) * 256 + threadIdx.x;
        unsigned short h, l;
        if (id < 16384) {                    // W1: [128,128]
            int k = id >> 7, n = id & 127;
            bfsplit(W1[id], h, l);
            Wth1[n * KD + k] = h;
            Wtl1[n * KD + k] = l;
        } else {                             // W2: [128,64]
            int id2 = id - 16384;
            int k = id2 >> 6, n = id2 & 63;
            bfsplit(W2[id2], h, l);
            Wth2[n * KD + k] = h;
            Wtl2[n * KD + k] = l;
        }
        return;
    }

    // -------- edge scatter into slack buckets; record = (row<<16)|col --------
    lh[threadIdx.x] = 0;
    __syncthreads();
    int base = (int)blockIdx.x * CHUNK;
#pragma unroll
    for (int r = 0; r < CHUNK / 256; ++r) {
        int e = base + r * 256 + threadIdx.x;
        if (e < E) atomicAdd(&lh[col[e] >> 8], 1);
    }
    __syncthreads();
    int c0 = lh[threadIdx.x];
    lbase[threadIdx.x] = c0 ? (threadIdx.x * BCAP + atomicAdd(&gcur[threadIdx.x], c0)) : 0;
    __syncthreads();
    lh[threadIdx.x] = 0;  // reuse as local running offset
    __syncthreads();
#pragma unroll
    for (int r = 0; r < CHUNK / 256; ++r) {
        int e = base + r * 256 + threadIdx.x;
        if (e < E) {
            int c = col[e];
            int b = c >> 8;
            int slot = lbase[b] + atomicAdd(&lh[b], 1);
            bpack[slot] = ((unsigned int)row[e] << 16) | (unsigned int)c;
        }
    }
}

// ------- MERGED: bucket_csr (blocks [0,NBUCKET)) + layer-1 GEMM (rest) -------
__global__ __launch_bounds__(256) void csr_and_gemm1(
        const unsigned int* __restrict__ bpack, const int* __restrict__ gcur,
        int* __restrict__ rowptr, float* __restrict__ dinv,
        unsigned short* __restrict__ srow, int N, int E, int NBUCKET,
        const float* __restrict__ X,
        const unsigned short* __restrict__ Wth,
        const unsigned short* __restrict__ Wtl,
        unsigned short* __restrict__ G) {
    __shared__ int s[256];
    __shared__ int lh[256];
    __shared__ int lcur[256];
    __shared__ int sh_bstart;

    if ((int)blockIdx.x < NBUCKET) {
        // ---------------- CSR build ----------------
        int b = blockIdx.x;
        int t = threadIdx.x;
        int cntb = gcur[t];          // zero-based count (R15)
        s[t] = cntb;
        __syncthreads();
        for (int off = 1; off < 256; off <<= 1) {
            int tv = (t >= off) ? s[t - off] : 0;
            __syncthreads();
            s[t] += tv;
            __syncthreads();
        }
        if (t == b) sh_bstart = s[t] - cntb;  // exclusive prefix of this bucket
        if (b == 0 && t == 0) rowptr[N] = E;
        lh[t] = 0;
        __syncthreads();
        int bstart = sh_bstart;
        int nE = gcur[b];
        int base = b * BCAP;
        for (int i = t; i < nE; i += 256)
            atomicAdd(&lh[bpack[base + i] & 255], 1);
        __syncthreads();
        int v = lh[t];
        s[t] = v;
        __syncthreads();
        for (int off = 1; off < 256; off <<= 1) {
            int tv = (t >= off) ? s[t - off] : 0;
            __syncthreads();
            s[t] += tv;
            __syncthreads();
        }
        int myStart = bstart + s[t] - v;  // exclusive
        int node = (b << 8) + t;
        if (node < N) {
            rowptr[node] = myStart;
            dinv[node] = rsqrtf(1.0f + (float)v);
        }
        lcur[t] = myStart;
        __syncthreads();
        for (int i = t; i < nE; i += 256) {
            unsigned int p = bpack[base + i];
            int slot = atomicAdd(&lcur[p & 255], 1);
            srow[slot] = (unsigned short)(p >> 16);
        }
    } else {
        // ---------------- layer-1 GEMM (split-A, 3 MFMAs, no dinv) ----------
        constexpr int FOUT = 128, NT = 8;
        int wave = threadIdx.x >> 6;
        int lane = threadIdx.x & 63;
        int row0 = (((int)blockIdx.x - NBUCKET) * 4 + wave) * 16;
        if (row0 >= N) return;
        int m = lane & 15;
        int quad = lane >> 4;

        float4v acc[NT];
#pragma unroll
        for (int ct = 0; ct < NT; ++ct) acc[ct] = (float4v){0.f, 0.f, 0.f, 0.f};

        const float* xrow = X + (size_t)(row0 + m) * KD + quad * 8;

#pragma unroll
        for (int ks = 0; ks < 4; ++ks) {
            float4 xa = *(const float4*)(xrow + ks * 32);
            float4 xb = *(const float4*)(xrow + ks * 32 + 4);
            float xs[8] = {xa.x, xa.y, xa.z, xa.w, xb.x, xb.y, xb.z, xb.w};
            short8 ah, al;
#pragma unroll
            for (int j = 0; j < 8; ++j) {
                unsigned short h, l;
                bfsplit(xs[j], h, l);
                ah[j] = (short)h;
                al[j] = (short)l;
            }
            int koff = ks * 32 + quad * 8;
#pragma unroll
            for (int ct = 0; ct < NT; ++ct) {
                short8 bh = *(const short8*)(Wth + (size_t)(ct * 16 + m) * KD + koff);
                short8 bl = *(const short8*)(Wtl + (size_t)(ct * 16 + m) * KD + koff);
                acc[ct] = __builtin_amdgcn_mfma_f32_16x16x32_bf16(ah, bh, acc[ct], 0, 0, 0);
                acc[ct] = __builtin_amdgcn_mfma_f32_16x16x32_bf16(al, bh, acc[ct], 0, 0, 0);
                acc[ct] = __builtin_amdgcn_mfma_f32_16x16x32_bf16(ah, bl, acc[ct], 0, 0, 0);
            }
        }

#pragma unroll
        for (int r = 0; r < 4; ++r) {
            int row = row0 + quad * 4 + r;
#pragma unroll
            for (int ct = 0; ct < NT; ++ct) {
                G[(size_t)row * FOUT + ct * 16 + m] = f2bf(acc[ct][r]);
            }
        }
    }
}

// ------------- FUSED: layer-1 gather + relu + layer-2 GEMM (R17) -------------
// Quarter-wave (16 lanes x dwordx4 = 256B row) per node; block = 256 thr =
// 16 nodes = one 16-row MFMA tile. Window-broadcast srow/dinv, granule 4.
// R23: predication via dr[j] zeroing (fmaf(0,v,s)==s; v finite) -- 1 cndmask
// per edge instead of 4 uint masks, bit-identical.
__global__ __launch_bounds__(256) void gather128_gemm2(
        const int* __restrict__ rowptr,
        const unsigned short* __restrict__ srow,
        const unsigned int* __restrict__ G,      // g1 bf16x2
        const float* __restrict__ dinv,
        const float* __restrict__ bias,          // b1
        const unsigned short* __restrict__ Wth,  // wth2
        const unsigned short* __restrict__ Wtl,  // wtl2
        unsigned short* __restrict__ G2,         // g2 out (bf16, dinv-scaled)
        int N, int E) {
    __shared__ unsigned int lhs[16 * 64];  // 16 rows x 128 bf16 (packed pairs)
    __shared__ float ldinv[16];

    int lane = threadIdx.x & 63;
    int l16 = threadIdx.x & 15;
    int q = threadIdx.x >> 4;            // block-local node 0..15
    int node = (int)blockIdx.x * 16 + q;
    bool valid = node < N;
    int nc = valid ? node : 0;
    int beg = rowptr[nc];
    int end = rowptr[nc + 1];
    int deg = valid ? (end - beg) : 0;
    float dn = dinv[nc];
    if (l16 == 0) ldinv[q] = dn;

    const uint4v* Gv = (const uint4v*)G;  // row = 16 uint4

    // self-loop (x dinv[n]); lane covers features [l16*8, l16*8+8)
    uint4v s0 = Gv[(size_t)nc * 16 + l16];
    float ac[8];
    {
        float2 v0 = bfpair(s0[0]), v1 = bfpair(s0[1]);
        float2 v2 = bfpair(s0[2]), v3 = bfpair(s0[3]);
        ac[0] = v0.x * dn; ac[1] = v0.y * dn;
        ac[2] = v1.x * dn; ac[3] = v1.y * dn;
        ac[4] = v2.x * dn; ac[5] = v2.y * dn;
        ac[6] = v3.x * dn; ac[7] = v3.y * dn;
    }

    int dm = max(deg, __shfl_xor(deg, 16));
    dm = max(dm, __shfl_xor(dm, 32));    // wave-uniform over 4 quarters

    for (int w = 0; w < dm; w += 16) {
        // one lane-indexed load covers 16 edge row-ids for this quarter
        int li = w + l16;
        li = (li < deg) ? li : (deg > 0 ? deg - 1 : 0);
        li += beg;
        li = (li < E) ? li : (E - 1);
        int rv = (int)srow[li];
        float dv = dinv[rv];
        int lim = dm - w;                // uniform
        for (int g = 0; g < 16 && g < lim; g += 4) {
            uint4v u[4];
            float dr[4];
#pragma unroll
            for (int j = 0; j < 4; ++j) {
                int src = (lane & 48) | (g + j);   // broadcast within own quarter
                int r = __shfl(rv, src);
                dr[j] = __shfl(dv, src);
                u[j] = Gv[(size_t)r * 16 + l16];
            }
            float sa[8] = {0.f, 0.f, 0.f, 0.f, 0.f, 0.f, 0.f, 0.f};
#pragma unroll
            for (int j = 0; j < 4; ++j) {
                // R23: mask the multiplier, not the data (bit-identical)
                float drm = ((w + g + j) < deg) ? dr[j] : 0.f;
#pragma unroll
                for (int c = 0; c < 4; ++c) {
                    float2 v = bfpair(u[j][c]);
                    sa[2 * c]     = fmaf(drm, v.x, sa[2 * c]);
                    sa[2 * c + 1] = fmaf(drm, v.y, sa[2 * c + 1]);
                }
            }
#pragma unroll
            for (int c = 0; c < 8; ++c) ac[c] += sa[c];
        }
    }

    // epilogue: h = relu(ac*dn + b1) -> bf16 pack into LDS tile
    {
        float4 bv0 = ((const float4*)bias)[l16 * 2];
        float4 bv1 = ((const float4*)bias)[l16 * 2 + 1];
        float o[8];
        o[0] = ac[0] * dn + bv0.x; o[1] = ac[1] * dn + bv0.y;
        o[2] = ac[2] * dn + bv0.z; o[3] = ac[3] * dn + bv0.w;
        o[4] = ac[4] * dn + bv1.x; o[5] = ac[5] * dn + bv1.y;
        o[6] = ac[6] * dn + bv1.z; o[7] = ac[7] * dn + bv1.w;
#pragma unroll
        for (int c = 0; c < 8; ++c) o[c] = fmaxf(o[c], 0.f);
        int lb = q * 64 + l16 * 4;
        lhs[lb + 0] = packbf(o[0], o[1]);
        lhs[lb + 1] = packbf(o[2], o[3]);
        lhs[lb + 2] = packbf(o[4], o[5]);
        lhs[lb + 3] = packbf(o[6], o[7]);
    }
    __syncthreads();

    // ---------------- fused gemm2: wave ct -> 16x16 output tile ----------------
    int ct = threadIdx.x >> 6;           // 0..3 -> cols [16ct, 16ct+16)
    int m = lane & 15;
    int quad = lane >> 4;

    float4v acc = (float4v){0.f, 0.f, 0.f, 0.f};
#pragma unroll
    for (int ks = 0; ks < 4; ++ks) {
        short8 a = *(const short8*)&lhs[m * 64 + ks * 16 + quad * 4];
        int koff = ks * 32 + quad * 8;
        short8 bh = *(const short8*)(Wth + (size_t)(ct * 16 + m) * KD + koff);
        short8 bl = *(const short8*)(Wtl + (size_t)(ct * 16 + m) * KD + koff);
        acc = __builtin_amdgcn_mfma_f32_16x16x32_bf16(a, bh, acc, 0, 0, 0);
        acc = __builtin_amdgcn_mfma_f32_16x16x32_bf16(a, bl, acc, 0, 0, 0);
    }

#pragma unroll
    for (int r = 0; r < 4; ++r) {
        int rr = quad * 4 + r;           // block-local output row
        int gnode = (int)blockIdx.x * 16 + rr;
        if (gnode < N) {
            G2[(size_t)gnode * 64 + ct * 16 + m] = f2bf(acc[r] * ldinv[rr]);
        }
    }
}

// F=64 (R15 structure): quarter-wave per node (16 lanes x 8B = 128B row) ->
// one row-load retires 4 edges. Window-broadcast; g2 pre-scaled by source
// dinv. R23: predication via multiplier m in {0,1} (fmaf(1,v,s) rounds == s+v;
// fmaf(0,v,s)==s) -- bit-identical, fewer cndmask. fp32 nt out.
template <bool RELU>
__global__ __launch_bounds__(256) void gather64(const int* __restrict__ rowptr,
                                                const unsigned short* __restrict__ srow,
                                                const unsigned int* __restrict__ G,  // bf16x2
                                                const float* __restrict__ dinv,
                                                const float* __restrict__ bias,
                                                float* __restrict__ O, int N, int E) {
    int tid = blockIdx.x * 256 + (int)threadIdx.x;
    int node = tid >> 4;          // quarter-wave per node
    int lane = threadIdx.x & 63;
    int l16 = lane & 15;
    bool valid = node < N;
    int nc = valid ? node : (N - 1);
    int beg = rowptr[nc];
    int end = rowptr[nc + 1];
    int deg = valid ? (end - beg) : 0;

    // self-loop; row = 32 uints = 16 uint2
    uint2 s0 = ((const uint2*)G)[(size_t)nc * 16 + l16];
    float2 p0 = bfpair(s0.x), p1 = bfpair(s0.y);
    float ax = p0.x, ay = p0.y, az = p1.x, aw = p1.y;

    int dm = max(deg, __shfl_xor(deg, 16));
    dm = max(dm, __shfl_xor(dm, 32));   // wave-uniform over 4 quarters

    for (int w = 0; w < dm; w += 16) {
        int li = w + l16;
        li = (li < deg) ? li : (deg > 0 ? deg - 1 : 0);
        li += beg;
        li = (li < E) ? li : (E - 1);
        int rv = (int)srow[li];
        int lim = dm - w;
        for (int g = 0; g < 16 && g < lim; g += 8) {
            uint2 u[8];
#pragma unroll
            for (int j = 0; j < 8; ++j) {
                int src = (lane & 48) | (g + j);    // broadcast within own quarter
                int r = __shfl(rv, src);
                u[j] = ((const uint2*)G)[(size_t)r * 16 + l16];
            }
            float sx = 0.f, sy = 0.f, sz = 0.f, sw = 0.f;
#pragma unroll
            for (int j = 0; j < 8; ++j) {
                float mm = ((w + g + j) < deg) ? 1.f : 0.f;   // R23 mask-mult
                float2 v0 = bfpair(u[j].x), v1 = bfpair(u[j].y);
                sx = fmaf(mm, v0.x, sx);
                sy = fmaf(mm, v0.y, sy);
                sz = fmaf(mm, v1.x, sz);
                sw = fmaf(mm, v1.y, sw);
            }
            ax += sx; ay += sy; az += sz; aw += sw;
        }
    }
    if (!valid) return;
    float s = dinv[nc];
    float4 bv = ((const float4*)bias)[l16];
    float ox = ax * s + bv.x;
    float oy = ay * s + bv.y;
    float oz = az * s + bv.z;
    float ow = aw * s + bv.w;
    if (RELU) {
        ox = fmaxf(ox, 0.f); oy = fmaxf(oy, 0.f);
        oz = fmaxf(oz, 0.f); ow = fmaxf(ow, 0.f);
    }
    float4v o = {ox, oy, oz, ow};
    __builtin_nontemporal_store(o, (float4v*)O + (size_t)nc * 16 + l16);
}

extern "C" void kernel_launch(void* const* d_in, const int* in_sizes, int n_in,
                              void* d_out, int out_size, void* d_ws, size_t ws_size,
                              hipStream_t stream) {
    const float* x  = (const float*)d_in[0];
    const int*   ei = (const int*)d_in[1];   // int32
    const float* W1 = (const float*)d_in[2];
    const float* b1 = (const float*)d_in[3];
    const float* W2 = (const float*)d_in[4];
    const float* b2 = (const float*)d_in[5];
    float* out = (float*)d_out;

    int N = in_sizes[0] / 128;
    int E = in_sizes[1] / 2;
    const int* row = ei;       // edge_index[0]
    const int* col = ei + E;   // edge_index[1]

    // Workspace layout (all regions written before read each call)
    char* ws = (char*)d_ws;
    float* dinv   = (float*)(ws + 0x000000);             // 200 KB
    int*   rowptr = (int*)  (ws + 0x080000);             // 200 KB + 4
    int*   gcur   = (int*)  (ws + 0x0F9000);             // 1 KB
    unsigned short* srow = (unsigned short*)(ws + 0x100000);   // 1.6 MB
    unsigned short* g1 = (unsigned short*)(ws + 0x440000);     // 12.8 MB
    unsigned short* wth1 = (unsigned short*)(ws + 0x10C0000);  // 32 KB
    unsigned short* wtl1 = (unsigned short*)(ws + 0x10D0000);  // 32 KB
    unsigned short* wth2 = (unsigned short*)(ws + 0x10E0000);  // 16 KB
    unsigned short* wtl2 = (unsigned short*)(ws + 0x10F0000);  // 16 KB
    // Packed slack bucket buffer (256 x BCAP uints = 6.29 MB); consumed by
    // csr_and_gemm1, dead afterwards (h2 eliminated by R17 fusion).
    unsigned int* bpack = (unsigned int*)(ws + 0x1200000);     // 6.29 MB
    unsigned short* g2 = (unsigned short*)(ws + 0x2C00000);    // 6.4 MB

    int NB_BKT  = (E + CHUNK - 1) / CHUNK;   // 391
    int NBUCKET = (N + 255) / 256;           // 196
    int NB_GEMM1 = (N + 63) / 64;            // 782
    int NB_SETUP = 96;                       // 24576 transpose elems / 256

    // ---- gcur zero + merged scatter/setup + merged CSR/GEMM1 ----
    hipMemsetAsync(gcur, 0, 256 * sizeof(int), stream);
    scatter_setup<<<NB_BKT + NB_SETUP, 256, 0, stream>>>(
        row, col, gcur, bpack, E, NB_BKT, W1, wth1, wtl1, W2, wth2, wtl2);
    csr_and_gemm1<<<NBUCKET + NB_GEMM1, 256, 0, stream>>>(
        bpack, gcur, rowptr, dinv, srow, N, E, NBUCKET, x, wth1, wtl1, g1);

    int nb;
    // ---- fused layer-1 gather + relu + layer-2 GEMM (16 nodes/block) ----
    nb = (N + 15) / 16;
    gather128_gemm2<<<nb, 256, 0, stream>>>(rowptr, srow, (const unsigned int*)g1,
                                            dinv, b1, wth2, wtl2, g2, N, E);

    // ---- layer-2 gather (quarter-wave per node) ----
    nb = (N + 15) / 16;
    gather64<false><<<nb, 256, 0, stream>>>(rowptr, srow, (const unsigned int*)g2,
                                            dinv, b2, out, N, E);
}